// Round 13
// baseline (931.987 us; speedup 1.0000x reference)
//
#include <hip/hip_runtime.h>
#include <hip/hip_bf16.h>
#include <cstdint>
#include <cstddef>

#define L_SEQ   8192
#define DMODEL  768
#define NHEADS  24
#define DINNER  1536
#define NPROJ   3096      /* logical proj cols: 24 * 129 */
#define NPROJP  3200      /* padded weight rows for gload_lds */
#define XPS     3072      /* xp row stride: 24 heads * 128 (B@0..63, C@64..127) */
#define NTOK    16384
#define BT      8192      /* tokens per batch */
#define RMS_EPS 1.1920929e-07f

typedef __hip_bfloat16 bf16;
typedef __attribute__((ext_vector_type(8))) short bf8v;
typedef __attribute__((ext_vector_type(4))) float f4v;

__device__ __forceinline__ float clampf(float x, float lo, float hi) {
    return fminf(fmaxf(x, lo), hi);
}
__device__ __forceinline__ float bf2f(bf16 v) { return __bfloat162float(v); }
__device__ __forceinline__ bf16  f2bf(float v) { return __float2bfloat16(v); }
__device__ __forceinline__ short f2bs(float v) {
    bf16 b = __float2bfloat16(v);
    return *reinterpret_cast<short*>(&b);
}
__device__ __forceinline__ float bs2f(short v) {
    return __uint_as_float(((unsigned)(unsigned short)v) << 16);
}
__device__ __forceinline__ void st1(float* p, float v) { *p = v; }
__device__ __forceinline__ void st1(bf16* p, float v) { *p = f2bf(v); }
__device__ __forceinline__ void st4(bf16* p, float4 v) {
    p[0] = f2bf(v.x); p[1] = f2bf(v.y); p[2] = f2bf(v.z); p[3] = f2bf(v.w);
}

#define GLOAD16(gsrc, ldst) __builtin_amdgcn_global_load_lds( \
    (const __attribute__((address_space(1))) void*)(gsrc),    \
    (__attribute__((address_space(3))) void*)(ldst), 16, 0, 0)

// ---------------------------------------------------------------- weight cvt / zero
__global__ __launch_bounds__(256) void k_cvt(const float* __restrict__ s,
                                             bf16* __restrict__ d, int n4) {
    int i = blockIdx.x * 256 + threadIdx.x;
    if (i < n4) {
        float4 v = *(const float4*)&s[i * 4];
        st4(&d[i * 4], v);
    }
}
__global__ __launch_bounds__(256) void k_zero(bf16* __restrict__ d, int n) {
    int i = blockIdx.x * 256 + threadIdx.x;
    if (i < n) d[i] = f2bf(0.f);
}

// ---------------------------------------------------------------- RMSNorm (f32 in, bf16 out)
__global__ __launch_bounds__(256) void k_rmsnorm(const float* __restrict__ hs,
                                                 const float* __restrict__ w,
                                                 bf16* __restrict__ xn) {
    int t = blockIdx.x;
    const float* p = hs + (size_t)t * DMODEL;
    float s = 0.f;
    for (int i = threadIdx.x; i < DMODEL; i += 256) { float v = p[i]; s += v * v; }
    for (int off = 32; off; off >>= 1) s += __shfl_xor(s, off, 64);
    __shared__ float ws4[4];
    int lane = threadIdx.x & 63, wv = threadIdx.x >> 6;
    if (lane == 0) ws4[wv] = s;
    __syncthreads();
    s = ws4[0] + ws4[1] + ws4[2] + ws4[3];
    float r = 1.0f / sqrtf(s * (1.0f / DMODEL) + RMS_EPS);
    bf16* o = xn + (size_t)t * DMODEL;
    for (int i = threadIdx.x; i < DMODEL; i += 256) o[i] = f2bf(p[i] * r * w[i]);
}

// ---------------------------------------------------------------- MFMA GEMM  C[M,N] = A[M,K] @ B[N,K]^T + bias
// EPI 0: plain   EPI 1: +resid/clip/gate (f32 out)
// EPI 2: split xp store: q=col%129; q==0 -> dtb[row*24+h]; else xp[row*XPS + h*128 + q-1]
template <typename TC, int EPI>
__global__ __launch_bounds__(256) void k_mgemm(const bf16* __restrict__ A,
                                               const bf16* __restrict__ B,
                                               const float* __restrict__ bias,
                                               TC* __restrict__ C,
                                               int M, int N, int K,
                                               const float* __restrict__ resid,
                                               const float* __restrict__ gatep,
                                               bf16* __restrict__ dtb) {
    __shared__ short As[2][128 * 32];
    __shared__ short Bs[2][128 * 32];
    int tid = threadIdx.x;
    int lane = tid & 63, w = tid >> 6;

    int gx = gridDim.x, gy = gridDim.y;
    int bid = blockIdx.y * gx + blockIdx.x;
    int xcd = bid & 7, idx = bid >> 3;
    int bys = gy >> 3;
    int gby = bys < 8 ? bys : 8;
    int sg  = idx / (gx * gby);
    int rem = idx - sg * (gx * gby);
    int bx  = rem / gby;
    int byl = rem - bx * gby;
    int by  = xcd * bys + sg * gby + byl;
    int m0 = by * 128, n0 = bx * 128;

    int wm = (w >> 1) << 6, wn = (w & 1) << 6;

    const size_t rowskip = (size_t)16 * K * 2;
    const char* Ag = (const char*)(A + (size_t)(m0 + (w << 5) + (lane >> 2)) * K) + (lane & 3) * 16;
    const char* Bg = (const char*)(B + (size_t)(n0 + (w << 5) + (lane >> 2)) * K) + (lane & 3) * 16;
    short* Al0 = &As[0][(w << 5) * 32];
    short* Bl0 = &Bs[0][(w << 5) * 32];
    short* Al1 = &As[1][(w << 5) * 32];
    short* Bl1 = &Bs[1][(w << 5) * 32];

    f4v acc[4][4];
#pragma unroll
    for (int i = 0; i < 4; ++i)
#pragma unroll
        for (int j = 0; j < 4; ++j) acc[i][j] = (f4v){0.f, 0.f, 0.f, 0.f};

    auto stage = [&](int buf, int k0) {
        size_t kb = (size_t)k0 * 2;
        short* Al = buf ? Al1 : Al0;
        short* Bl = buf ? Bl1 : Bl0;
        GLOAD16(Ag + kb,           Al);
        GLOAD16(Ag + kb + rowskip, Al + 16 * 32);
        GLOAD16(Bg + kb,           Bl);
        GLOAD16(Bg + kb + rowskip, Bl + 16 * 32);
    };

    stage(0, 0);
    int cur = 0;
    int row16 = lane & 15, kg = (lane >> 4) << 3;
    for (int k0 = 0; k0 < K; k0 += 32) {
        __syncthreads();
        if (k0 + 32 < K) stage(cur ^ 1, k0 + 32);
        const short* Ab = As[cur];
        const short* Bb = Bs[cur];
        bf8v af[4], bfv[4];
#pragma unroll
        for (int fm = 0; fm < 4; ++fm)
            af[fm] = *(const bf8v*)&Ab[(wm + (fm << 4) + row16) * 32 + kg];
#pragma unroll
        for (int fn = 0; fn < 4; ++fn)
            bfv[fn] = *(const bf8v*)&Bb[(wn + (fn << 4) + row16) * 32 + kg];
#pragma unroll
        for (int fm = 0; fm < 4; ++fm)
#pragma unroll
            for (int fn = 0; fn < 4; ++fn)
                acc[fm][fn] = __builtin_amdgcn_mfma_f32_16x16x32_bf16(
                    af[fm], bfv[fn], acc[fm][fn], 0, 0, 0);
        cur ^= 1;
    }

    float gate = (EPI == 1) ? *gatep : 0.f;
    int rbase = m0 + wm + ((lane >> 4) << 2);
#pragma unroll
    for (int fn = 0; fn < 4; ++fn) {
        int col = n0 + wn + (fn << 4) + (lane & 15);
        if (col >= N) continue;
        float bc = bias[col];
        int hh = 0, dst = col;
        if (EPI == 2) {
            hh = col / 129;
            int q = col - hh * 129;
            dst = (q == 0) ? -1 : hh * 128 + q - 1;
        }
#pragma unroll
        for (int fm = 0; fm < 4; ++fm) {
#pragma unroll
            for (int r = 0; r < 4; ++r) {
                int row = rbase + (fm << 4) + r;
                float v = acc[fm][fn][r] + bc;
                if (EPI == 1) {
                    v = resid[(size_t)row * N + col] + clampf(v, -100.f, 100.f) * gate;
                    st1(&C[(size_t)row * N + col], v);
                } else if (EPI == 2) {
                    if (dst < 0) dtb[(size_t)row * 24 + hh] = f2bf(v);
                    else st1(&C[(size_t)row * XPS + dst], v);
                } else {
                    st1(&C[(size_t)row * N + col], v);
                }
            }
        }
    }
}

// ---------------------------------------------------------------- conv+SiLU (batch-local, 8 ch/thread)
__global__ __launch_bounds__(192) void k_conv8(const bf16* __restrict__ x,
                                               const float* __restrict__ cw,
                                               const float* __restrict__ cb,
                                               bf16* __restrict__ xc) {
    int c0 = threadIdx.x * 8;
    int r  = blockIdx.x;                 // 0..BT-1, batch-local
    float acc[8];
#pragma unroll
    for (int j = 0; j < 8; ++j) acc[j] = cb[c0 + j];
#pragma unroll
    for (int k = 0; k < 4; ++k) {
        int lp = r - 3 + k;
        if (lp < 0) continue;
        bf8v v = *(const bf8v*)(const void*)(x + (size_t)lp * DINNER + c0);
#pragma unroll
        for (int j = 0; j < 8; ++j)
            acc[j] += cw[(c0 + j) * 4 + k] * bs2f(v[j]);
    }
    bf8v o;
#pragma unroll
    for (int j = 0; j < 8; ++j) {
        float a = acc[j];
        o[j] = f2bs(a / (1.f + expf(-a)));
    }
    *(bf8v*)(xc + (size_t)r * DINNER + c0) = o;
}

// ---------------------------------------------------------------- per-(t,h): A value, 1/||B||, 1/||C||
__global__ __launch_bounds__(256) void k_prep(const bf16* __restrict__ xp,
                                              const bf16* __restrict__ dtb,
                                              const float* __restrict__ A_log,
                                              float* __restrict__ Aarr,
                                              float* __restrict__ invB,
                                              float* __restrict__ invC) {
    int wv = threadIdx.x >> 6, lane = threadIdx.x & 63;
    int idx = blockIdx.x * 4 + wv;
    int t = idx / 24, h = idx - t * 24;
    const bf16* base = xp + (size_t)t * XPS + h * 128;
    float b = bf2f(base[lane]), c = bf2f(base[64 + lane]);
    float sb = b * b, sc = c * c;
    for (int off = 32; off; off >>= 1) {
        sb += __shfl_xor(sb, off, 64);
        sc += __shfl_xor(sc, off, 64);
    }
    if (lane == 0) {
        invB[idx] = 1.f / fmaxf(sqrtf(sb), 1e-12f);
        invC[idx] = 1.f / fmaxf(sqrtf(sc), 1e-12f);
        float dt = clampf(bf2f(dtb[idx]), -10.f, 10.f);
        float dts = clampf(log1pf(expf(dt)), 0.01f, 10.f);
        float A = clampf(A_log[h], -2.3f, -0.01f) * dts;
        Aarr[idx] = clampf(A, -20.f, -0.001f);
    }
}

// ---------------------------------------------------------------- surprise (vectorized staging)
__global__ __launch_bounds__(256) void k_surprise_all(const bf16* __restrict__ xp,
                                                      const bf16* __restrict__ xc,
                                                      const float* __restrict__ invB,
                                                      float* __restrict__ cs) {
    int g = blockIdx.x;                 // 0..6143
    int cg = g / 24, h = g - cg * 24;   // cg: global chunk 0..255
    int b = cg >> 7, nl = cg & 127;
    int t0 = cg * 64;
    size_t cs_idx = (size_t)(b * 24 + h) * 128 + nl;
    __shared__ short Ws[64 * 72];   // B^T [s][c]
    __shared__ short Xt[64 * 72];   // X^T [d][c]
    int tid = threadIdx.x;
#pragma unroll
    for (int half = 0; half < 2; ++half) {
        int tau = tid + half * 256;
        int c = tau >> 3, s0 = (tau & 7) << 3;
        int t = t0 + c;
        float ib = invB[t * 24 + h];
        bf8v Bv = *(const bf8v*)(const void*)(xp + (size_t)t * XPS + h * 128 + s0);
        bf8v Xv = *(const bf8v*)(const void*)(xc + (size_t)t * DINNER + h * 64 + s0);
#pragma unroll
        for (int u = 0; u < 8; ++u) {
            Ws[(s0 + u) * 72 + c] = f2bs(bs2f(Bv[u]) * ib);
            Xt[(s0 + u) * 72 + c] = Xv[u];
        }
    }
    __syncthreads();
    int w = tid >> 6, lane = tid & 63;
    int r16 = lane & 15, kq = (lane >> 4) << 3;
    int strip = w << 4;
    f4v acc[4];
#pragma unroll
    for (int dt = 0; dt < 4; ++dt) acc[dt] = (f4v){0.f, 0.f, 0.f, 0.f};
#pragma unroll
    for (int ks = 0; ks < 2; ++ks) {
        bf8v af = *(const bf8v*)&Ws[(strip + r16) * 72 + ks * 32 + kq];
#pragma unroll
        for (int dt = 0; dt < 4; ++dt) {
            bf8v bf_ = *(const bf8v*)&Xt[((dt << 4) + r16) * 72 + ks * 32 + kq];
            acc[dt] = __builtin_amdgcn_mfma_f32_16x16x32_bf16(af, bf_, acc[dt], 0, 0, 0);
        }
    }
    float ss = 0.f;
#pragma unroll
    for (int dt = 0; dt < 4; ++dt)
#pragma unroll
        for (int r = 0; r < 4; ++r) ss += acc[dt][r] * acc[dt][r];
    for (int off = 32; off; off >>= 1) ss += __shfl_xor(ss, off, 64);
    __shared__ float ws4[4];
    if (lane == 0) ws4[w] = ss;
    __syncthreads();
    if (tid == 0) cs[cs_idx] = (ws4[0] + ws4[1] + ws4[2] + ws4[3]) * (1.f / 4096.f);
}

// ---------------------------------------------------------------- per-head EMA + alpha
__global__ __launch_bounds__(256) void k_alpha(const float* __restrict__ cs,
                                               const float* __restrict__ ema0,
                                               const float* __restrict__ l2ab,
                                               const float* __restrict__ l2b,
                                               float* __restrict__ alpha) {
    int h = blockIdx.x, tid = threadIdx.x;
    int b = tid >> 7, n = tid & 127;
    int gi = (b * 24 + h) * 128 + n;
    float v = cs[gi];
    float s = v;
    for (int off = 32; off; off >>= 1) s += __shfl_xor(s, off, 64);
    __shared__ float ws4[4];
    int lane = tid & 63, wv = tid >> 6;
    if (lane == 0) ws4[wv] = s;
    __syncthreads();
    float total = ws4[0] + ws4[1] + ws4[2] + ws4[3];
    float ema = 0.99f * ema0[h] + 0.01f * (total * (1.f / 256.f));
    float ab = 1.f - exp2f(clampf(l2ab[h], -3.32f, -0.015f));
    float beta = exp2f(clampf(l2b[h], -2.f, 2.f));
    float nz = v / (ema + 1e-6f);
    float boost = fmaxf(tanhf(beta * nz), 0.f);
    alpha[gi] = clampf(ab + (1.f - ab) * boost, 0.01f, 0.999f);
}

// ---------------------------------------------------------------- fused intra+hchunk (batch-local)
__global__ __launch_bounds__(256) void k_chunk(const bf16* __restrict__ xp,
                                               const bf16* __restrict__ xc,
                                               const float* __restrict__ invB,
                                               const float* __restrict__ invC,
                                               const float* __restrict__ Aarr,
                                               const float* __restrict__ alpha,
                                               bf16* __restrict__ ybuf,
                                               bf16* __restrict__ hf,
                                               float* __restrict__ dchunk,
                                               int b) {
    int g = blockIdx.x;                  // h*128 + nl
    int h = g >> 7, nl = g & 127;
    int t0 = nl * 64;                    // batch-local token
    size_t gidx = (size_t)(b * 24 + h) * 128 + nl;
    size_t hbase = (size_t)g * 4096;
    float alp = alpha[gidx];
    __shared__ short Cs[64 * 72];   // C rows [i][s]; later M [i][j]
    __shared__ short Bs[64 * 72];   // B rows [j][s]
    __shared__ short Ws[64 * 72];   // (dte·B)^T [s][c]
    __shared__ short Xt[64 * 72];   // X^T [d][c]
    __shared__ float Acs[64];
    __shared__ float dte[64];
    int tid = threadIdx.x;
    if (tid < 64) {
        float a = Aarr[(size_t)(t0 + tid) * 24 + h] * (1.f - alp);
        for (int off = 1; off < 64; off <<= 1) {
            float u = __shfl_up(a, off, 64);
            if (tid >= off) a += u;
        }
        Acs[tid] = a;
        float total = __shfl(a, 63, 64);
        dte[tid] = expf(total - a);
        if (tid == 0) dchunk[gidx] = expf(total);
    }
    __syncthreads();
#pragma unroll
    for (int half = 0; half < 2; ++half) {
        int tau = tid + half * 256;
        int c = tau >> 3, s0 = (tau & 7) << 3;
        int t = t0 + c;
        const bf16* bp = xp + (size_t)t * XPS + h * 128;
        float ib = invB[t * 24 + h], ic2 = invC[t * 24 + h];
        float dc = dte[c];
        bf8v Bv = *(const bf8v*)(const void*)(bp + s0);
        bf8v Cv = *(const bf8v*)(const void*)(bp + 64 + s0);
        bf8v Xv = *(const bf8v*)(const void*)(xc + (size_t)t * DINNER + h * 64 + s0);
        bf8v Bsc, Csc;
#pragma unroll
        for (int u = 0; u < 8; ++u) {
            float bv = bs2f(Bv[u]) * ib;
            Bsc[u] = f2bs(bv);
            Csc[u] = f2bs(bs2f(Cv[u]) * ic2);
            Ws[(s0 + u) * 72 + c] = f2bs(bv * dc);
            Xt[(s0 + u) * 72 + c] = Xv[u];
        }
        *(bf8v*)&Bs[c * 72 + s0] = Bsc;
        *(bf8v*)&Cs[c * 72 + s0] = Csc;
    }
    __syncthreads();
    int w = tid >> 6, lane = tid & 63;
    int r16 = lane & 15, kq = (lane >> 4) << 3;
    int strip = w << 4;
    f4v acb[4], ach[4];
#pragma unroll
    for (int jt = 0; jt < 4; ++jt) {
        acb[jt] = (f4v){0.f, 0.f, 0.f, 0.f};
        ach[jt] = (f4v){0.f, 0.f, 0.f, 0.f};
    }
#pragma unroll
    for (int ks = 0; ks < 2; ++ks) {
        bf8v afc = *(const bf8v*)&Cs[(strip + r16) * 72 + ks * 32 + kq];
        bf8v afw = *(const bf8v*)&Ws[(strip + r16) * 72 + ks * 32 + kq];
#pragma unroll
        for (int jt = 0; jt < 4; ++jt) {
            bf8v bb = *(const bf8v*)&Bs[((jt << 4) + r16) * 72 + ks * 32 + kq];
            acb[jt] = __builtin_amdgcn_mfma_f32_16x16x32_bf16(afc, bb, acb[jt], 0, 0, 0);
            bf8v xx = *(const bf8v*)&Xt[((jt << 4) + r16) * 72 + ks * 32 + kq];
            ach[jt] = __builtin_amdgcn_mfma_f32_16x16x32_bf16(afw, xx, ach[jt], 0, 0, 0);
        }
    }
    int rbase = strip + ((lane >> 4) << 2);
#pragma unroll
    for (int dt = 0; dt < 4; ++dt) {
        int d = (dt << 4) + r16;
#pragma unroll
        for (int r = 0; r < 4; ++r)
            hf[hbase + (size_t)(rbase + r) * 64 + d] = f2bf(ach[dt][r]);
    }
    __syncthreads();
    short* Ms = Cs;
#pragma unroll
    for (int jt = 0; jt < 4; ++jt) {
        int j = (jt << 4) + r16;
        float aj = Acs[j];
#pragma unroll
        for (int r = 0; r < 4; ++r) {
            int i = rbase + r;
            float m = (j <= i) ? expf(Acs[i] - aj) * acb[jt][r] : 0.f;
            Ms[i * 72 + j] = f2bs(m);
        }
    }
    __syncthreads();
    f4v acy[4];
#pragma unroll
    for (int dt = 0; dt < 4; ++dt) acy[dt] = (f4v){0.f, 0.f, 0.f, 0.f};
#pragma unroll
    for (int ks = 0; ks < 2; ++ks) {
        bf8v afm = *(const bf8v*)&Ms[(strip + r16) * 72 + ks * 32 + kq];
#pragma unroll
        for (int dt = 0; dt < 4; ++dt) {
            bf8v xx = *(const bf8v*)&Xt[((dt << 4) + r16) * 72 + ks * 32 + kq];
            acy[dt] = __builtin_amdgcn_mfma_f32_16x16x32_bf16(afm, xx, acy[dt], 0, 0, 0);
        }
    }
#pragma unroll
    for (int dt = 0; dt < 4; ++dt) {
        int d = (dt << 4) + r16;
#pragma unroll
        for (int r = 0; r < 4; ++r) {
            int i = rbase + r;
            ybuf[(size_t)(t0 + i) * DINNER + h * 64 + d] = f2bf(acy[dt][r]);
        }
    }
}

// ---------------------------------------------------------------- chunk scan (batch-local, carry-free, prefetched)
__global__ __launch_bounds__(256) void k_scan(bf16* __restrict__ hf,
                                              const float* __restrict__ dchunk,
                                              int b) {
    int h = blockIdx.x >> 4;                         // 0..23
    int e = ((blockIdx.x & 15) << 8) + threadIdx.x;  // 0..4095
    float c = 0.f;
    size_t a = (size_t)h * 128 * 4096 + e;
    float v = bf2f(hf[a]);
    const float* dcp = dchunk + (size_t)(b * 24 + h) * 128;
    for (int nl = 0; nl < 128; ++nl) {
        float dc = dcp[nl];
        float vn = (nl + 1 < 128) ? bf2f(hf[a + 4096]) : 0.f;
        hf[a] = f2bf(c);
        c = dc * c + v;
        v = vn;
        a += 4096;
    }
}

// ---------------------------------------------------------------- Y_inter + gate (batch-local)
__global__ __launch_bounds__(256) void k_inter(const bf16* __restrict__ xp,
                                               const float* __restrict__ invC,
                                               const float* __restrict__ Aarr,
                                               const float* __restrict__ alpha,
                                               const bf16* __restrict__ hf,
                                               const bf16* __restrict__ zbuf,
                                               bf16* __restrict__ ybuf,
                                               int b) {
    int g = blockIdx.x;                  // h*128 + nl
    int h = g >> 7, nl = g & 127;
    int t0 = nl * 64;
    size_t gidx = (size_t)(b * 24 + h) * 128 + nl;
    size_t hbase = (size_t)g * 4096;
    float alp = alpha[gidx];
    __shared__ short Cs[64 * 72];
    __shared__ short Ht[64 * 72];
    __shared__ float dfs[64];
    int tid = threadIdx.x;
    if (tid < 64) {
        float a = Aarr[(size_t)(t0 + tid) * 24 + h] * (1.f - alp);
        for (int off = 1; off < 64; off <<= 1) {
            float u = __shfl_up(a, off, 64);
            if (tid >= off) a += u;
        }
        dfs[tid] = expf(a);
    }
#pragma unroll
    for (int half = 0; half < 2; ++half) {
        int tau = tid + half * 256;
        int c = tau >> 3, s0 = (tau & 7) << 3;
        int t = t0 + c;
        float ic2 = invC[t * 24 + h];
        bf8v Cv = *(const bf8v*)(const void*)(xp + (size_t)t * XPS + h * 128 + 64 + s0);
        bf8v Hv = *(const bf8v*)(const void*)(hf + hbase + (size_t)c * 64 + s0);
        bf8v Csc;
#pragma unroll
        for (int u = 0; u < 8; ++u) {
            Csc[u] = f2bs(bs2f(Cv[u]) * ic2);
            Ht[(s0 + u) * 72 + c] = Hv[u];
        }
        *(bf8v*)&Cs[c * 72 + s0] = Csc;
    }
    __syncthreads();
    int w = tid >> 6, lane = tid & 63;
    int r16 = lane & 15, kq = (lane >> 4) << 3;
    int strip = w << 4;
    f4v acc[4];
#pragma unroll
    for (int dt = 0; dt < 4; ++dt) acc[dt] = (f4v){0.f, 0.f, 0.f, 0.f};
#pragma unroll
    for (int ks = 0; ks < 2; ++ks) {
        bf8v af = *(const bf8v*)&Cs[(strip + r16) * 72 + ks * 32 + kq];
#pragma unroll
        for (int dt = 0; dt < 4; ++dt) {
            bf8v hfr = *(const bf8v*)&Ht[((dt << 4) + r16) * 72 + ks * 32 + kq];
            acc[dt] = __builtin_amdgcn_mfma_f32_16x16x32_bf16(af, hfr, acc[dt], 0, 0, 0);
        }
    }
    int ibase = strip + ((lane >> 4) << 2);
#pragma unroll
    for (int dt = 0; dt < 4; ++dt) {
        int d = (dt << 4) + r16;
#pragma unroll
        for (int r = 0; r < 4; ++r) {
            int i = ibase + r;
            float df = dfs[i];
            size_t yoff = (size_t)(t0 + i) * DINNER + h * 64 + d;
            float Y = clampf(bf2f(ybuf[yoff]) + df * acc[dt][r], -100.f, 100.f);
            float zz = bf2f(zbuf[yoff]);
            ybuf[yoff] = f2bf(Y / (1.f + expf(-zz)));
        }
    }
}

// ---------------------------------------------------------------- launch
extern "C" void kernel_launch(void* const* d_in, const int* in_sizes, int n_in,
                              void* d_out, int out_size, void* d_ws, size_t ws_size,
                              hipStream_t stream) {
    const float* hs     = (const float*)d_in[0];
    const float* norm_w = (const float*)d_in[1];
    const float* w1     = (const float*)d_in[2];
    const float* b1     = (const float*)d_in[3];
    const float* cw     = (const float*)d_in[4];
    const float* cbias  = (const float*)d_in[5];
    const float* w2     = (const float*)d_in[6];
    const float* b2     = (const float*)d_in[7];
    const float* A_log  = (const float*)d_in[8];
    const float* l2ab   = (const float*)d_in[9];
    const float* l2b    = (const float*)d_in[10];
    const float* ema0   = (const float*)d_in[11];
    const float* w3     = (const float*)d_in[12];
    const float* b3     = (const float*)d_in[13];
    const float* rg     = (const float*)d_in[14];
    float* out = (float*)d_out;

    // footprint ~190.8 MB; proven ws_size >= ~204 MB (R10 ran a larger layout)
    char* base = (char*)d_ws;
    size_t off = 0;
    auto alloc = [&](size_t bytes) -> void* {
        void* p = base + off;
        off += (bytes + 255) & ~(size_t)255;
        return p;
    };
    bf16* w1bf  = (bf16*)alloc((size_t)2 * DINNER * DMODEL * 2);
    bf16* w2bf  = (bf16*)alloc((size_t)NPROJP * DINNER * 2);
    bf16* w3bf  = (bf16*)alloc((size_t)DMODEL * DINNER * 2);
    bf16* xnb   = (bf16*)alloc((size_t)BT * DMODEL * 2);       // per-batch rmsnorm out
    bf16* ybuf  = (bf16*)alloc((size_t)BT * DINNER * 2);       // per-batch Y / pre-conv x
    bf16* hf    = (bf16*)alloc((size_t)NHEADS * 128 * 4096 * 2); // per-batch chunk states
    bf16* dtb   = (bf16*)alloc((size_t)NTOK * 24 * 2);
    float* cs   = (float*)alloc((size_t)6144 * 4);
    float* alp  = (float*)alloc((size_t)6144 * 4);
    float* dch  = (float*)alloc((size_t)6144 * 4);
    bf16* xp    = (bf16*)alloc((size_t)NTOK * XPS * 2);
    float* Aarr = (float*)alloc((size_t)NTOK * 24 * 4);
    float* invB = (float*)alloc((size_t)NTOK * 24 * 4);
    float* invC = (float*)alloc((size_t)NTOK * 24 * 4);
    bf16* xbuf  = ybuf;                    // pre-conv x aliases ybuf
    bf16* xc_all = (bf16*)d_out;           // xc for all tokens lives in d_out

    {
        int n1 = 2 * DINNER * DMODEL / 4, n2 = NPROJ * DINNER / 4, n3 = DMODEL * DINNER / 4;
        k_cvt<<<(n1 + 255) / 256, 256, 0, stream>>>(w1, w1bf, n1);
        k_cvt<<<(n2 + 255) / 256, 256, 0, stream>>>(w2, w2bf, n2);
        k_cvt<<<(n3 + 255) / 256, 256, 0, stream>>>(w3, w3bf, n3);
        int nz = (NPROJP - NPROJ) * DINNER;
        k_zero<<<(nz + 255) / 256, 256, 0, stream>>>(w2bf + (size_t)NPROJ * DINNER, nz);
    }

    const dim3 gXb(DINNER / 128, BT / 128);          // 12 x 64
    const dim3 gOb(DMODEL / 128, BT / 128);          // 6 x 64
    const dim3 gPall(NPROJP / 128, NTOK / 128);      // 25 x 128

    // ---------------- phase 1: front-end per batch; xc cached into d_out
    for (int bt = 0; bt < 2; ++bt) {
        size_t t0 = (size_t)bt * BT;
        k_rmsnorm<<<BT, 256, 0, stream>>>(hs + t0 * DMODEL, norm_w, xnb);
        k_mgemm<bf16, 0><<<gXb, 256, 0, stream>>>(xnb, w1bf, b1, xbuf,
                                                  BT, DINNER, DMODEL, nullptr, nullptr, nullptr);
        k_conv8<<<BT, 192, 0, stream>>>(xbuf, cw, cbias, xc_all + t0 * DINNER);
    }
    // x_proj over all tokens (split dt/B/C layout)
    k_mgemm<bf16, 2><<<gPall, 256, 0, stream>>>(xc_all, w2bf, b2, xp,
                                                NTOK, NPROJ, DINNER, nullptr, nullptr, dtb);
    k_prep<<<NTOK * 24 / 4, 256, 0, stream>>>(xp, dtb, A_log, Aarr, invB, invC);
    k_surprise_all<<<6144, 256, 0, stream>>>(xp, xc_all, invB, cs);
    k_alpha<<<24, 256, 0, stream>>>(cs, ema0, l2ab, l2b, alp);

    // ---------------- phase 2: SSM + output per batch
    for (int bt = 0; bt < 2; ++bt) {
        size_t t0 = (size_t)bt * BT;
        bf16* xc = xc_all + t0 * DINNER;
        bf16* zseg = xc;                   // z overwrites dead xc region of d_out
        const bf16* xpS = xp + t0 * XPS;
        const float* AarrS = Aarr + t0 * 24;
        const float* invBS = invB + t0 * 24;
        const float* invCS = invC + t0 * 24;
        k_chunk<<<NHEADS * 128, 256, 0, stream>>>(xpS, xc, invBS, invCS, AarrS, alp,
                                                  ybuf, hf, dch, bt);
        k_rmsnorm<<<BT, 256, 0, stream>>>(hs + t0 * DMODEL, norm_w, xnb);
        k_mgemm<bf16, 0><<<gXb, 256, 0, stream>>>(xnb, w1bf + (size_t)DINNER * DMODEL,
                                                  b1 + DINNER, zseg,
                                                  BT, DINNER, DMODEL, nullptr, nullptr, nullptr);
        k_scan<<<384, 256, 0, stream>>>(hf, dch, bt);
        k_inter<<<NHEADS * 128, 256, 0, stream>>>(xpS, invCS, AarrS, alp, hf, zseg, ybuf, bt);
        k_mgemm<float, 1><<<gOb, 256, 0, stream>>>(ybuf, w3bf, b3, out + t0 * DMODEL,
                                                   BT, DMODEL, DINNER,
                                                   hs + t0 * DMODEL, rg, nullptr);
    }
}

// Round 14
// 914.660 us; speedup vs baseline: 1.0189x; 1.0189x over previous
//
#include <hip/hip_runtime.h>
#include <hip/hip_bf16.h>
#include <cstdint>
#include <cstddef>

#define L_SEQ   8192
#define DMODEL  768
#define NHEADS  24
#define DINNER  1536
#define NPROJ   3096      /* logical proj cols: 24 * 129 */
#define NPROJP  3200      /* padded weight rows for gload_lds */
#define NPROJ2  3264      /* padded xp row stride: 24 * 136 */
#define HSTR    136       /* per-head stride in xp: dt@0, B@8, C@72 */
#define NTOK    16384
#define BT      8192      /* tokens per batch */
#define RMS_EPS 1.1920929e-07f

typedef __hip_bfloat16 bf16;
typedef __attribute__((ext_vector_type(8))) short bf8v;
typedef __attribute__((ext_vector_type(4))) float f4v;

__device__ __forceinline__ float clampf(float x, float lo, float hi) {
    return fminf(fmaxf(x, lo), hi);
}
__device__ __forceinline__ float bf2f(bf16 v) { return __bfloat162float(v); }
__device__ __forceinline__ bf16  f2bf(float v) { return __float2bfloat16(v); }
__device__ __forceinline__ short f2bs(float v) {
    bf16 b = __float2bfloat16(v);
    return *reinterpret_cast<short*>(&b);
}
__device__ __forceinline__ float bs2f(short v) {
    return __uint_as_float(((unsigned)(unsigned short)v) << 16);
}
__device__ __forceinline__ void st1(float* p, float v) { *p = v; }
__device__ __forceinline__ void st1(bf16* p, float v) { *p = f2bf(v); }
__device__ __forceinline__ void st4(bf16* p, float4 v) {
    p[0] = f2bf(v.x); p[1] = f2bf(v.y); p[2] = f2bf(v.z); p[3] = f2bf(v.w);
}

#define GLOAD16(gsrc, ldst) __builtin_amdgcn_global_load_lds( \
    (const __attribute__((address_space(1))) void*)(gsrc),    \
    (__attribute__((address_space(3))) void*)(ldst), 16, 0, 0)

// ---------------------------------------------------------------- weight cvt / zero
__global__ __launch_bounds__(256) void k_cvt(const float* __restrict__ s,
                                             bf16* __restrict__ d, int n4) {
    int i = blockIdx.x * 256 + threadIdx.x;
    if (i < n4) {
        float4 v = *(const float4*)&s[i * 4];
        st4(&d[i * 4], v);
    }
}
__global__ __launch_bounds__(256) void k_zero(bf16* __restrict__ d, int n) {
    int i = blockIdx.x * 256 + threadIdx.x;
    if (i < n) d[i] = f2bf(0.f);
}

// ---------------------------------------------------------------- RMSNorm (f32 in, bf16 out)
__global__ __launch_bounds__(256) void k_rmsnorm(const float* __restrict__ hs,
                                                 const float* __restrict__ w,
                                                 bf16* __restrict__ xn) {
    int t = blockIdx.x;
    const float* p = hs + (size_t)t * DMODEL;
    float s = 0.f;
    for (int i = threadIdx.x; i < DMODEL; i += 256) { float v = p[i]; s += v * v; }
    for (int off = 32; off; off >>= 1) s += __shfl_xor(s, off, 64);
    __shared__ float ws4[4];
    int lane = threadIdx.x & 63, wv = threadIdx.x >> 6;
    if (lane == 0) ws4[wv] = s;
    __syncthreads();
    s = ws4[0] + ws4[1] + ws4[2] + ws4[3];
    float r = 1.0f / sqrtf(s * (1.0f / DMODEL) + RMS_EPS);
    bf16* o = xn + (size_t)t * DMODEL;
    for (int i = threadIdx.x; i < DMODEL; i += 256) o[i] = f2bf(p[i] * r * w[i]);
}

// ---------------------------------------------------------------- MFMA GEMM  C[M,N] = A[M,K] @ B[N,K]^T + bias
// EPI 0: plain   EPI 1: +resid/clip/gate (f32 out)
// EPI 2: padded-xp store: h=col/129, q=col%129; dst = h*136 + (q?q+7:0)
template <typename TC, int EPI>
__global__ __launch_bounds__(256) void k_mgemm(const bf16* __restrict__ A,
                                               const bf16* __restrict__ B,
                                               const float* __restrict__ bias,
                                               TC* __restrict__ C,
                                               int M, int N, int K,
                                               const float* __restrict__ resid,
                                               const float* __restrict__ gatep) {
    __shared__ short As[2][128 * 32];
    __shared__ short Bs[2][128 * 32];
    int tid = threadIdx.x;
    int lane = tid & 63, w = tid >> 6;

    int gx = gridDim.x, gy = gridDim.y;
    int bid = blockIdx.y * gx + blockIdx.x;
    int xcd = bid & 7, idx = bid >> 3;
    int bys = gy >> 3;
    int gby = bys < 8 ? bys : 8;
    int sg  = idx / (gx * gby);
    int rem = idx - sg * (gx * gby);
    int bx  = rem / gby;
    int byl = rem - bx * gby;
    int by  = xcd * bys + sg * gby + byl;
    int m0 = by * 128, n0 = bx * 128;

    int wm = (w >> 1) << 6, wn = (w & 1) << 6;

    const size_t rowskip = (size_t)16 * K * 2;
    const char* Ag = (const char*)(A + (size_t)(m0 + (w << 5) + (lane >> 2)) * K) + (lane & 3) * 16;
    const char* Bg = (const char*)(B + (size_t)(n0 + (w << 5) + (lane >> 2)) * K) + (lane & 3) * 16;
    short* Al0 = &As[0][(w << 5) * 32];
    short* Bl0 = &Bs[0][(w << 5) * 32];
    short* Al1 = &As[1][(w << 5) * 32];
    short* Bl1 = &Bs[1][(w << 5) * 32];

    f4v acc[4][4];
#pragma unroll
    for (int i = 0; i < 4; ++i)
#pragma unroll
        for (int j = 0; j < 4; ++j) acc[i][j] = (f4v){0.f, 0.f, 0.f, 0.f};

    auto stage = [&](int buf, int k0) {
        size_t kb = (size_t)k0 * 2;
        short* Al = buf ? Al1 : Al0;
        short* Bl = buf ? Bl1 : Bl0;
        GLOAD16(Ag + kb,           Al);
        GLOAD16(Ag + kb + rowskip, Al + 16 * 32);
        GLOAD16(Bg + kb,           Bl);
        GLOAD16(Bg + kb + rowskip, Bl + 16 * 32);
    };

    stage(0, 0);
    int cur = 0;
    int row16 = lane & 15, kg = (lane >> 4) << 3;
    for (int k0 = 0; k0 < K; k0 += 32) {
        __syncthreads();
        if (k0 + 32 < K) stage(cur ^ 1, k0 + 32);
        const short* Ab = As[cur];
        const short* Bb = Bs[cur];
        bf8v af[4], bfv[4];
#pragma unroll
        for (int fm = 0; fm < 4; ++fm)
            af[fm] = *(const bf8v*)&Ab[(wm + (fm << 4) + row16) * 32 + kg];
#pragma unroll
        for (int fn = 0; fn < 4; ++fn)
            bfv[fn] = *(const bf8v*)&Bb[(wn + (fn << 4) + row16) * 32 + kg];
#pragma unroll
        for (int fm = 0; fm < 4; ++fm)
#pragma unroll
            for (int fn = 0; fn < 4; ++fn)
                acc[fm][fn] = __builtin_amdgcn_mfma_f32_16x16x32_bf16(
                    af[fm], bfv[fn], acc[fm][fn], 0, 0, 0);
        cur ^= 1;
    }

    float gate = (EPI == 1) ? *gatep : 0.f;
    int rbase = m0 + wm + ((lane >> 4) << 2);
#pragma unroll
    for (int fn = 0; fn < 4; ++fn) {
        int col = n0 + wn + (fn << 4) + (lane & 15);
        if (col >= N) continue;
        float bc = bias[col];
        int dst = col;
        if (EPI == 2) {
            int hh = col / 129, q = col - hh * 129;
            dst = hh * HSTR + (q == 0 ? 0 : q + 7);
        }
#pragma unroll
        for (int fm = 0; fm < 4; ++fm) {
#pragma unroll
            for (int r = 0; r < 4; ++r) {
                int row = rbase + (fm << 4) + r;
                float v = acc[fm][fn][r] + bc;
                if (EPI == 1) {
                    v = resid[(size_t)row * N + col] + clampf(v, -100.f, 100.f) * gate;
                    st1(&C[(size_t)row * N + col], v);
                } else if (EPI == 2) {
                    st1(&C[(size_t)row * NPROJ2 + dst], v);
                } else {
                    st1(&C[(size_t)row * N + col], v);
                }
            }
        }
    }
}

// ---------------------------------------------------------------- conv+SiLU (batch-local, 8 ch/thread)
__global__ __launch_bounds__(192) void k_conv8(const bf16* __restrict__ x,
                                               const float* __restrict__ cw,
                                               const float* __restrict__ cb,
                                               bf16* __restrict__ xc) {
    int c0 = threadIdx.x * 8;
    int r  = blockIdx.x;                 // 0..BT-1, batch-local
    float acc[8];
#pragma unroll
    for (int j = 0; j < 8; ++j) acc[j] = cb[c0 + j];
#pragma unroll
    for (int k = 0; k < 4; ++k) {
        int lp = r - 3 + k;
        if (lp < 0) continue;
        bf8v v = *(const bf8v*)(const void*)(x + (size_t)lp * DINNER + c0);
#pragma unroll
        for (int j = 0; j < 8; ++j)
            acc[j] += cw[(c0 + j) * 4 + k] * bs2f(v[j]);
    }
    bf8v o;
#pragma unroll
    for (int j = 0; j < 8; ++j) {
        float a = acc[j];
        o[j] = f2bs(a / (1.f + expf(-a)));
    }
    *(bf8v*)(xc + (size_t)r * DINNER + c0) = o;
}

// ---------------------------------------------------------------- per-(t,h): A value, 1/||B||, 1/||C||
__global__ __launch_bounds__(256) void k_prep(const bf16* __restrict__ xp,
                                              const float* __restrict__ A_log,
                                              float* __restrict__ Aarr,
                                              float* __restrict__ invB,
                                              float* __restrict__ invC) {
    int wv = threadIdx.x >> 6, lane = threadIdx.x & 63;
    int idx = blockIdx.x * 4 + wv;
    int t = idx / 24, h = idx - t * 24;
    const bf16* base = xp + (size_t)t * NPROJ2 + h * HSTR;
    float b = bf2f(base[8 + lane]), c = bf2f(base[72 + lane]);
    float sb = b * b, sc = c * c;
    for (int off = 32; off; off >>= 1) {
        sb += __shfl_xor(sb, off, 64);
        sc += __shfl_xor(sc, off, 64);
    }
    if (lane == 0) {
        invB[idx] = 1.f / fmaxf(sqrtf(sb), 1e-12f);
        invC[idx] = 1.f / fmaxf(sqrtf(sc), 1e-12f);
        float dt = clampf(bf2f(base[0]), -10.f, 10.f);
        float dts = clampf(log1pf(expf(dt)), 0.01f, 10.f);
        float A = clampf(A_log[h], -2.3f, -0.01f) * dts;
        Aarr[idx] = clampf(A, -20.f, -0.001f);
    }
}

// ---------------------------------------------------------------- surprise (vectorized staging)
__global__ __launch_bounds__(256) void k_surprise_all(const bf16* __restrict__ xp,
                                                      const bf16* __restrict__ xc,
                                                      const float* __restrict__ invB,
                                                      float* __restrict__ cs) {
    int g = blockIdx.x;                 // 0..6143
    int cg = g / 24, h = g - cg * 24;   // cg: global chunk 0..255
    int b = cg >> 7, nl = cg & 127;
    int t0 = cg * 64;
    size_t cs_idx = (size_t)(b * 24 + h) * 128 + nl;
    __shared__ short Ws[64 * 72];   // B^T [s][c]
    __shared__ short Xt[64 * 72];   // X^T [d][c]
    int tid = threadIdx.x;
#pragma unroll
    for (int half = 0; half < 2; ++half) {
        int tau = tid + half * 256;
        int c = tau >> 3, s0 = (tau & 7) << 3;
        int t = t0 + c;
        float ib = invB[t * 24 + h];
        bf8v Bv = *(const bf8v*)(const void*)(xp + (size_t)t * NPROJ2 + h * HSTR + 8 + s0);
        bf8v Xv = *(const bf8v*)(const void*)(xc + (size_t)t * DINNER + h * 64 + s0);
#pragma unroll
        for (int u = 0; u < 8; ++u) {
            Ws[(s0 + u) * 72 + c] = f2bs(bs2f(Bv[u]) * ib);
            Xt[(s0 + u) * 72 + c] = Xv[u];
        }
    }
    __syncthreads();
    int w = tid >> 6, lane = tid & 63;
    int r16 = lane & 15, kq = (lane >> 4) << 3;
    int strip = w << 4;
    f4v acc[4];
#pragma unroll
    for (int dt = 0; dt < 4; ++dt) acc[dt] = (f4v){0.f, 0.f, 0.f, 0.f};
#pragma unroll
    for (int ks = 0; ks < 2; ++ks) {
        bf8v af = *(const bf8v*)&Ws[(strip + r16) * 72 + ks * 32 + kq];
#pragma unroll
        for (int dt = 0; dt < 4; ++dt) {
            bf8v bf_ = *(const bf8v*)&Xt[((dt << 4) + r16) * 72 + ks * 32 + kq];
            acc[dt] = __builtin_amdgcn_mfma_f32_16x16x32_bf16(af, bf_, acc[dt], 0, 0, 0);
        }
    }
    float ss = 0.f;
#pragma unroll
    for (int dt = 0; dt < 4; ++dt)
#pragma unroll
        for (int r = 0; r < 4; ++r) ss += acc[dt][r] * acc[dt][r];
    for (int off = 32; off; off >>= 1) ss += __shfl_xor(ss, off, 64);
    __shared__ float ws4[4];
    if (lane == 0) ws4[w] = ss;
    __syncthreads();
    if (tid == 0) cs[cs_idx] = (ws4[0] + ws4[1] + ws4[2] + ws4[3]) * (1.f / 4096.f);
}

// ---------------------------------------------------------------- per-head EMA + alpha
__global__ __launch_bounds__(256) void k_alpha(const float* __restrict__ cs,
                                               const float* __restrict__ ema0,
                                               const float* __restrict__ l2ab,
                                               const float* __restrict__ l2b,
                                               float* __restrict__ alpha) {
    int h = blockIdx.x, tid = threadIdx.x;
    int b = tid >> 7, n = tid & 127;
    int gi = (b * 24 + h) * 128 + n;
    float v = cs[gi];
    float s = v;
    for (int off = 32; off; off >>= 1) s += __shfl_xor(s, off, 64);
    __shared__ float ws4[4];
    int lane = tid & 63, wv = tid >> 6;
    if (lane == 0) ws4[wv] = s;
    __syncthreads();
    float total = ws4[0] + ws4[1] + ws4[2] + ws4[3];
    float ema = 0.99f * ema0[h] + 0.01f * (total * (1.f / 256.f));
    float ab = 1.f - exp2f(clampf(l2ab[h], -3.32f, -0.015f));
    float beta = exp2f(clampf(l2b[h], -2.f, 2.f));
    float nz = v / (ema + 1e-6f);
    float boost = fmaxf(tanhf(beta * nz), 0.f);
    alpha[gi] = clampf(ab + (1.f - ab) * boost, 0.01f, 0.999f);
}

// ---------------------------------------------------------------- fused intra+hchunk (batch-local)
__global__ __launch_bounds__(256) void k_chunk(const bf16* __restrict__ xp,
                                               const bf16* __restrict__ xc,
                                               const float* __restrict__ invB,
                                               const float* __restrict__ invC,
                                               const float* __restrict__ Aarr,
                                               const float* __restrict__ alpha,
                                               bf16* __restrict__ ybuf,
                                               bf16* __restrict__ hf,
                                               float* __restrict__ dchunk,
                                               int b) {
    int g = blockIdx.x;                  // h*128 + nl
    int h = g >> 7, nl = g & 127;
    int t0 = nl * 64;                    // batch-local token
    size_t gidx = (size_t)(b * 24 + h) * 128 + nl;
    size_t hbase = (size_t)g * 4096;
    float alp = alpha[gidx];
    __shared__ short Cs[64 * 72];   // C rows [i][s]; later M [i][j]
    __shared__ short Bs[64 * 72];   // B rows [j][s]
    __shared__ short Ws[64 * 72];   // (dte·B)^T [s][c]
    __shared__ short Xt[64 * 72];   // X^T [d][c]
    __shared__ float Acs[64];
    __shared__ float dte[64];
    int tid = threadIdx.x;
    if (tid < 64) {
        float a = Aarr[(size_t)(t0 + tid) * 24 + h] * (1.f - alp);
        for (int off = 1; off < 64; off <<= 1) {
            float u = __shfl_up(a, off, 64);
            if (tid >= off) a += u;
        }
        Acs[tid] = a;
        float total = __shfl(a, 63, 64);
        dte[tid] = expf(total - a);
        if (tid == 0) dchunk[gidx] = expf(total);
    }
    __syncthreads();
#pragma unroll
    for (int half = 0; half < 2; ++half) {
        int tau = tid + half * 256;
        int c = tau >> 3, s0 = (tau & 7) << 3;
        int t = t0 + c;
        const bf16* bp = xp + (size_t)t * NPROJ2 + h * HSTR;
        float ib = invB[t * 24 + h], ic2 = invC[t * 24 + h];
        float dc = dte[c];
        bf8v Bv = *(const bf8v*)(const void*)(bp + 8 + s0);
        bf8v Cv = *(const bf8v*)(const void*)(bp + 72 + s0);
        bf8v Xv = *(const bf8v*)(const void*)(xc + (size_t)t * DINNER + h * 64 + s0);
        bf8v Bsc, Csc;
#pragma unroll
        for (int u = 0; u < 8; ++u) {
            float bv = bs2f(Bv[u]) * ib;
            Bsc[u] = f2bs(bv);
            Csc[u] = f2bs(bs2f(Cv[u]) * ic2);
            Ws[(s0 + u) * 72 + c] = f2bs(bv * dc);
            Xt[(s0 + u) * 72 + c] = Xv[u];
        }
        *(bf8v*)&Bs[c * 72 + s0] = Bsc;
        *(bf8v*)&Cs[c * 72 + s0] = Csc;
    }
    __syncthreads();
    int w = tid >> 6, lane = tid & 63;
    int r16 = lane & 15, kq = (lane >> 4) << 3;
    int strip = w << 4;
    f4v acb[4], ach[4];
#pragma unroll
    for (int jt = 0; jt < 4; ++jt) {
        acb[jt] = (f4v){0.f, 0.f, 0.f, 0.f};
        ach[jt] = (f4v){0.f, 0.f, 0.f, 0.f};
    }
#pragma unroll
    for (int ks = 0; ks < 2; ++ks) {
        bf8v afc = *(const bf8v*)&Cs[(strip + r16) * 72 + ks * 32 + kq];
        bf8v afw = *(const bf8v*)&Ws[(strip + r16) * 72 + ks * 32 + kq];
#pragma unroll
        for (int jt = 0; jt < 4; ++jt) {
            bf8v bb = *(const bf8v*)&Bs[((jt << 4) + r16) * 72 + ks * 32 + kq];
            acb[jt] = __builtin_amdgcn_mfma_f32_16x16x32_bf16(afc, bb, acb[jt], 0, 0, 0);
            bf8v xx = *(const bf8v*)&Xt[((jt << 4) + r16) * 72 + ks * 32 + kq];
            ach[jt] = __builtin_amdgcn_mfma_f32_16x16x32_bf16(afw, xx, ach[jt], 0, 0, 0);
        }
    }
    int rbase = strip + ((lane >> 4) << 2);
#pragma unroll
    for (int dt = 0; dt < 4; ++dt) {
        int d = (dt << 4) + r16;
#pragma unroll
        for (int r = 0; r < 4; ++r)
            hf[hbase + (size_t)(rbase + r) * 64 + d] = f2bf(ach[dt][r]);
    }
    __syncthreads();
    short* Ms = Cs;
#pragma unroll
    for (int jt = 0; jt < 4; ++jt) {
        int j = (jt << 4) + r16;
        float aj = Acs[j];
#pragma unroll
        for (int r = 0; r < 4; ++r) {
            int i = rbase + r;
            float m = (j <= i) ? expf(Acs[i] - aj) * acb[jt][r] : 0.f;
            Ms[i * 72 + j] = f2bs(m);
        }
    }
    __syncthreads();
    f4v acy[4];
#pragma unroll
    for (int dt = 0; dt < 4; ++dt) acy[dt] = (f4v){0.f, 0.f, 0.f, 0.f};
#pragma unroll
    for (int ks = 0; ks < 2; ++ks) {
        bf8v afm = *(const bf8v*)&Ms[(strip + r16) * 72 + ks * 32 + kq];
#pragma unroll
        for (int dt = 0; dt < 4; ++dt) {
            bf8v xx = *(const bf8v*)&Xt[((dt << 4) + r16) * 72 + ks * 32 + kq];
            acy[dt] = __builtin_amdgcn_mfma_f32_16x16x32_bf16(afm, xx, acy[dt], 0, 0, 0);
        }
    }
#pragma unroll
    for (int dt = 0; dt < 4; ++dt) {
        int d = (dt << 4) + r16;
#pragma unroll
        for (int r = 0; r < 4; ++r) {
            int i = rbase + r;
            ybuf[(size_t)(t0 + i) * DINNER + h * 64 + d] = f2bf(acy[dt][r]);
        }
    }
}

// ---------------------------------------------------------------- chunk scan (batch-local, depth-4 pipeline)
__global__ __launch_bounds__(256) void k_scan(bf16* __restrict__ hf,
                                              const float* __restrict__ dchunk,
                                              int b) {
    int h = blockIdx.x >> 4;                         // 0..23
    int e = ((blockIdx.x & 15) << 8) + threadIdx.x;  // 0..4095
    size_t abase = (size_t)h * 128 * 4096 + e;
    const float* dcp = dchunk + (size_t)(b * 24 + h) * 128;
    float c = 0.f;
    float v0 = bf2f(hf[abase]);
    float v1 = bf2f(hf[abase + 1 * 4096]);
    float v2 = bf2f(hf[abase + 2 * 4096]);
    float v3 = bf2f(hf[abase + 3 * 4096]);
    for (int nl = 0; nl < 128; nl += 4) {
        float p0 = (nl + 4 < 128) ? bf2f(hf[abase + (size_t)(nl + 4) * 4096]) : 0.f;
        float p1 = (nl + 5 < 128) ? bf2f(hf[abase + (size_t)(nl + 5) * 4096]) : 0.f;
        float p2 = (nl + 6 < 128) ? bf2f(hf[abase + (size_t)(nl + 6) * 4096]) : 0.f;
        float p3 = (nl + 7 < 128) ? bf2f(hf[abase + (size_t)(nl + 7) * 4096]) : 0.f;
        hf[abase + (size_t)nl * 4096] = f2bf(c);
        c = dcp[nl] * c + v0;
        hf[abase + (size_t)(nl + 1) * 4096] = f2bf(c);
        c = dcp[nl + 1] * c + v1;
        hf[abase + (size_t)(nl + 2) * 4096] = f2bf(c);
        c = dcp[nl + 2] * c + v2;
        hf[abase + (size_t)(nl + 3) * 4096] = f2bf(c);
        c = dcp[nl + 3] * c + v3;
        v0 = p0; v1 = p1; v2 = p2; v3 = p3;
    }
}

// ---------------------------------------------------------------- Y_inter + gate (batch-local)
__global__ __launch_bounds__(256) void k_inter(const bf16* __restrict__ xp,
                                               const float* __restrict__ invC,
                                               const float* __restrict__ Aarr,
                                               const float* __restrict__ alpha,
                                               const bf16* __restrict__ hf,
                                               const bf16* __restrict__ zbuf,
                                               bf16* __restrict__ ybuf,
                                               int b) {
    int g = blockIdx.x;                  // h*128 + nl
    int h = g >> 7, nl = g & 127;
    int t0 = nl * 64;
    size_t gidx = (size_t)(b * 24 + h) * 128 + nl;
    size_t hbase = (size_t)g * 4096;
    float alp = alpha[gidx];
    __shared__ short Cs[64 * 72];
    __shared__ short Ht[64 * 72];
    __shared__ float dfs[64];
    int tid = threadIdx.x;
    if (tid < 64) {
        float a = Aarr[(size_t)(t0 + tid) * 24 + h] * (1.f - alp);
        for (int off = 1; off < 64; off <<= 1) {
            float u = __shfl_up(a, off, 64);
            if (tid >= off) a += u;
        }
        dfs[tid] = expf(a);
    }
#pragma unroll
    for (int half = 0; half < 2; ++half) {
        int tau = tid + half * 256;
        int c = tau >> 3, s0 = (tau & 7) << 3;
        int t = t0 + c;
        float ic2 = invC[t * 24 + h];
        bf8v Cv = *(const bf8v*)(const void*)(xp + (size_t)t * NPROJ2 + h * HSTR + 72 + s0);
        bf8v Hv = *(const bf8v*)(const void*)(hf + hbase + (size_t)c * 64 + s0);
        bf8v Csc;
#pragma unroll
        for (int u = 0; u < 8; ++u) {
            Csc[u] = f2bs(bs2f(Cv[u]) * ic2);
            Ht[(s0 + u) * 72 + c] = Hv[u];
        }
        *(bf8v*)&Cs[c * 72 + s0] = Csc;
    }
    __syncthreads();
    int w = tid >> 6, lane = tid & 63;
    int r16 = lane & 15, kq = (lane >> 4) << 3;
    int strip = w << 4;
    f4v acc[4];
#pragma unroll
    for (int dt = 0; dt < 4; ++dt) acc[dt] = (f4v){0.f, 0.f, 0.f, 0.f};
#pragma unroll
    for (int ks = 0; ks < 2; ++ks) {
        bf8v af = *(const bf8v*)&Cs[(strip + r16) * 72 + ks * 32 + kq];
#pragma unroll
        for (int dt = 0; dt < 4; ++dt) {
            bf8v hfr = *(const bf8v*)&Ht[((dt << 4) + r16) * 72 + ks * 32 + kq];
            acc[dt] = __builtin_amdgcn_mfma_f32_16x16x32_bf16(af, hfr, acc[dt], 0, 0, 0);
        }
    }
    int ibase = strip + ((lane >> 4) << 2);
#pragma unroll
    for (int dt = 0; dt < 4; ++dt) {
        int d = (dt << 4) + r16;
#pragma unroll
        for (int r = 0; r < 4; ++r) {
            int i = ibase + r;
            float df = dfs[i];
            size_t yoff = (size_t)(t0 + i) * DINNER + h * 64 + d;
            float Y = clampf(bf2f(ybuf[yoff]) + df * acc[dt][r], -100.f, 100.f);
            float zz = bf2f(zbuf[yoff]);
            ybuf[yoff] = f2bf(Y / (1.f + expf(-zz)));
        }
    }
}

// ---------------------------------------------------------------- launch
extern "C" void kernel_launch(void* const* d_in, const int* in_sizes, int n_in,
                              void* d_out, int out_size, void* d_ws, size_t ws_size,
                              hipStream_t stream) {
    const float* hs     = (const float*)d_in[0];
    const float* norm_w = (const float*)d_in[1];
    const float* w1     = (const float*)d_in[2];
    const float* b1     = (const float*)d_in[3];
    const float* cw     = (const float*)d_in[4];
    const float* cbias  = (const float*)d_in[5];
    const float* w2     = (const float*)d_in[6];
    const float* b2     = (const float*)d_in[7];
    const float* A_log  = (const float*)d_in[8];
    const float* l2ab   = (const float*)d_in[9];
    const float* l2b    = (const float*)d_in[10];
    const float* ema0   = (const float*)d_in[11];
    const float* w3     = (const float*)d_in[12];
    const float* b3     = (const float*)d_in[13];
    const float* rg     = (const float*)d_in[14];
    float* out = (float*)d_out;

    // footprint ~191.6 MB; proven ws_size >= ~199.4 MB (R10 ran a larger layout)
    char* base = (char*)d_ws;
    size_t off = 0;
    auto alloc = [&](size_t bytes) -> void* {
        void* p = base + off;
        off += (bytes + 255) & ~(size_t)255;
        return p;
    };
    bf16* w1bf  = (bf16*)alloc((size_t)2 * DINNER * DMODEL * 2);
    bf16* w2bf  = (bf16*)alloc((size_t)NPROJP * DINNER * 2);
    bf16* w3bf  = (bf16*)alloc((size_t)DMODEL * DINNER * 2);
    bf16* xnb   = (bf16*)alloc((size_t)BT * DMODEL * 2);         // per-batch rmsnorm out
    bf16* ybuf  = (bf16*)alloc((size_t)BT * DINNER * 2);         // per-batch Y / pre-conv x
    bf16* hf    = (bf16*)alloc((size_t)NHEADS * 128 * 4096 * 2); // per-batch chunk states
    float* cs   = (float*)alloc((size_t)6144 * 4);
    float* alp  = (float*)alloc((size_t)6144 * 4);
    float* dch  = (float*)alloc((size_t)6144 * 4);
    bf16* xp    = (bf16*)alloc((size_t)NTOK * NPROJ2 * 2);
    float* Aarr = (float*)alloc((size_t)NTOK * 24 * 4);
    float* invB = (float*)alloc((size_t)NTOK * 24 * 4);
    float* invC = (float*)alloc((size_t)NTOK * 24 * 4);
    bf16* xbuf  = ybuf;                    // pre-conv x aliases ybuf
    bf16* xc_all = (bf16*)d_out;           // xc for all tokens lives in d_out

    {
        int n1 = 2 * DINNER * DMODEL / 4, n2 = NPROJ * DINNER / 4, n3 = DMODEL * DINNER / 4;
        k_cvt<<<(n1 + 255) / 256, 256, 0, stream>>>(w1, w1bf, n1);
        k_cvt<<<(n2 + 255) / 256, 256, 0, stream>>>(w2, w2bf, n2);
        k_cvt<<<(n3 + 255) / 256, 256, 0, stream>>>(w3, w3bf, n3);
        int nz = (NPROJP - NPROJ) * DINNER;
        k_zero<<<(nz + 255) / 256, 256, 0, stream>>>(w2bf + (size_t)NPROJ * DINNER, nz);
    }

    const dim3 gXb(DINNER / 128, BT / 128);          // 12 x 64
    const dim3 gOb(DMODEL / 128, BT / 128);          // 6 x 64
    const dim3 gPall(NPROJP / 128, NTOK / 128);      // 25 x 128

    // ---------------- phase 1: front-end per batch; xc cached into d_out
    for (int bt = 0; bt < 2; ++bt) {
        size_t t0 = (size_t)bt * BT;
        k_rmsnorm<<<BT, 256, 0, stream>>>(hs + t0 * DMODEL, norm_w, xnb);
        k_mgemm<bf16, 0><<<gXb, 256, 0, stream>>>(xnb, w1bf, b1, xbuf,
                                                  BT, DINNER, DMODEL, nullptr, nullptr);
        k_conv8<<<BT, 192, 0, stream>>>(xbuf, cw, cbias, xc_all + t0 * DINNER);
    }
    // x_proj over all tokens (padded inline-dt layout)
    k_mgemm<bf16, 2><<<gPall, 256, 0, stream>>>(xc_all, w2bf, b2, xp,
                                                NTOK, NPROJ, DINNER, nullptr, nullptr);
    k_prep<<<NTOK * 24 / 4, 256, 0, stream>>>(xp, A_log, Aarr, invB, invC);
    k_surprise_all<<<6144, 256, 0, stream>>>(xp, xc_all, invB, cs);
    k_alpha<<<24, 256, 0, stream>>>(cs, ema0, l2ab, l2b, alp);

    // ---------------- phase 2: batch 1 first (xnb still holds batch-1 xn), then batch 0
    for (int pass = 0; pass < 2; ++pass) {
        int bt = 1 - pass;
        size_t t0 = (size_t)bt * BT;
        bf16* xc = xc_all + t0 * DINNER;
        bf16* zseg = xc;                   // z overwrites dead xc region of d_out
        const bf16* xpS = xp + t0 * NPROJ2;
        const float* AarrS = Aarr + t0 * 24;
        const float* invBS = invB + t0 * 24;
        const float* invCS = invC + t0 * 24;
        k_chunk<<<NHEADS * 128, 256, 0, stream>>>(xpS, xc, invBS, invCS, AarrS, alp,
                                                  ybuf, hf, dch, bt);
        if (bt == 0)   // batch-1 xn persists from phase 1; batch 0 must recompute
            k_rmsnorm<<<BT, 256, 0, stream>>>(hs + t0 * DMODEL, norm_w, xnb);
        k_mgemm<bf16, 0><<<gXb, 256, 0, stream>>>(xnb, w1bf + (size_t)DINNER * DMODEL,
                                                  b1 + DINNER, zseg,
                                                  BT, DINNER, DMODEL, nullptr, nullptr);
        k_scan<<<384, 256, 0, stream>>>(hf, dch, bt);
        k_inter<<<NHEADS * 128, 256, 0, stream>>>(xpS, invCS, AarrS, alp, hf, zseg, ybuf, bt);
        k_mgemm<float, 1><<<gOb, 256, 0, stream>>>(ybuf, w3bf, b3, out + t0 * DMODEL,
                                                   BT, DMODEL, DINNER,
                                                   hs + t0 * DMODEL, rg);
    }
}

// Round 15
// 784.090 us; speedup vs baseline: 1.1886x; 1.1665x over previous
//
#include <hip/hip_runtime.h>
#include <hip/hip_bf16.h>
#include <cstdint>
#include <cstddef>

#define L_SEQ   8192
#define DMODEL  768
#define NHEADS  24
#define DINNER  1536
#define NPROJ   3096      /* logical proj cols: 24 * 129 */
#define NPROJP  3200      /* padded weight rows for gload_lds */
#define XPS     3072      /* xp row stride: 24 heads * 128 (B@0..63, C@64..127) */
#define NTOK    16384
#define BT      8192      /* tokens per batch */
#define RMS_EPS 1.1920929e-07f

typedef __hip_bfloat16 bf16;
typedef __attribute__((ext_vector_type(8))) short bf8v;
typedef __attribute__((ext_vector_type(4))) float f4v;

__device__ __forceinline__ float clampf(float x, float lo, float hi) {
    return fminf(fmaxf(x, lo), hi);
}
__device__ __forceinline__ float bf2f(bf16 v) { return __bfloat162float(v); }
__device__ __forceinline__ bf16  f2bf(float v) { return __float2bfloat16(v); }
__device__ __forceinline__ short f2bs(float v) {
    bf16 b = __float2bfloat16(v);
    return *reinterpret_cast<short*>(&b);
}
__device__ __forceinline__ float bs2f(short v) {
    return __uint_as_float(((unsigned)(unsigned short)v) << 16);
}
__device__ __forceinline__ void st1(float* p, float v) { *p = v; }
__device__ __forceinline__ void st1(bf16* p, float v) { *p = f2bf(v); }
__device__ __forceinline__ void st4(bf16* p, float4 v) {
    p[0] = f2bf(v.x); p[1] = f2bf(v.y); p[2] = f2bf(v.z); p[3] = f2bf(v.w);
}

#define GLOAD16(gsrc, ldst) __builtin_amdgcn_global_load_lds( \
    (const __attribute__((address_space(1))) void*)(gsrc),    \
    (__attribute__((address_space(3))) void*)(ldst), 16, 0, 0)

// ---------------------------------------------------------------- weight cvt / zero / dt-slice
__global__ __launch_bounds__(256) void k_cvt(const float* __restrict__ s,
                                             bf16* __restrict__ d, int n4) {
    int i = blockIdx.x * 256 + threadIdx.x;
    if (i < n4) {
        float4 v = *(const float4*)&s[i * 4];
        st4(&d[i * 4], v);
    }
}
__global__ __launch_bounds__(256) void k_zero(bf16* __restrict__ d, int n) {
    int i = blockIdx.x * 256 + threadIdx.x;
    if (i < n) d[i] = f2bf(0.f);
}
// wdt[128][1536]: rows h<24 = w2 row h*129 (bf16), rows 24..127 zero; bdt[128]
__global__ __launch_bounds__(256) void k_wdt(const float* __restrict__ w2,
                                             const float* __restrict__ b2,
                                             bf16* __restrict__ wdt,
                                             float* __restrict__ bdt) {
    int i = blockIdx.x * 256 + threadIdx.x;   // element of wdt, 128*1536
    if (i < 128 * DINNER) {
        int h = i / DINNER, c = i - h * DINNER;
        wdt[i] = f2bf(h < 24 ? w2[(size_t)(h * 129) * DINNER + c] : 0.f);
    }
    if (i < 128) bdt[i] = (i < 24) ? b2[i * 129] : 0.f;
}

// ---------------------------------------------------------------- RMSNorm (f32 in, bf16 out)
__global__ __launch_bounds__(256) void k_rmsnorm(const float* __restrict__ hs,
                                                 const float* __restrict__ w,
                                                 bf16* __restrict__ xn) {
    int t = blockIdx.x;
    const float* p = hs + (size_t)t * DMODEL;
    float s = 0.f;
    for (int i = threadIdx.x; i < DMODEL; i += 256) { float v = p[i]; s += v * v; }
    for (int off = 32; off; off >>= 1) s += __shfl_xor(s, off, 64);
    __shared__ float ws4[4];
    int lane = threadIdx.x & 63, wv = threadIdx.x >> 6;
    if (lane == 0) ws4[wv] = s;
    __syncthreads();
    s = ws4[0] + ws4[1] + ws4[2] + ws4[3];
    float r = 1.0f / sqrtf(s * (1.0f / DMODEL) + RMS_EPS);
    bf16* o = xn + (size_t)t * DMODEL;
    for (int i = threadIdx.x; i < DMODEL; i += 256) o[i] = f2bf(p[i] * r * w[i]);
}

// ---------------------------------------------------------------- MFMA GEMM  C[M,N] = A[M,K] @ B[N,K]^T + bias
// EPI 0: plain   EPI 1: +resid/clip/gate (f32 out)
// EPI 2: xp store: h=col/129, q=col%129; q==0 skipped; dst = h*128 + q-1 (64B-aligned runs)
template <typename TC, int EPI>
__global__ __launch_bounds__(256) void k_mgemm(const bf16* __restrict__ A,
                                               const bf16* __restrict__ B,
                                               const float* __restrict__ bias,
                                               TC* __restrict__ C,
                                               int M, int N, int K,
                                               const float* __restrict__ resid,
                                               const float* __restrict__ gatep) {
    __shared__ short As[2][128 * 32];
    __shared__ short Bs[2][128 * 32];
    int tid = threadIdx.x;
    int lane = tid & 63, w = tid >> 6;

    int gx = gridDim.x, gy = gridDim.y;
    int bid = blockIdx.y * gx + blockIdx.x;
    int xcd = bid & 7, idx = bid >> 3;
    int bys = gy >> 3;
    int gby = bys < 8 ? bys : 8;
    int sg  = idx / (gx * gby);
    int rem = idx - sg * (gx * gby);
    int bx  = rem / gby;
    int byl = rem - bx * gby;
    int by  = xcd * bys + sg * gby + byl;
    int m0 = by * 128, n0 = bx * 128;

    int wm = (w >> 1) << 6, wn = (w & 1) << 6;

    const size_t rowskip = (size_t)16 * K * 2;
    const char* Ag = (const char*)(A + (size_t)(m0 + (w << 5) + (lane >> 2)) * K) + (lane & 3) * 16;
    const char* Bg = (const char*)(B + (size_t)(n0 + (w << 5) + (lane >> 2)) * K) + (lane & 3) * 16;
    short* Al0 = &As[0][(w << 5) * 32];
    short* Bl0 = &Bs[0][(w << 5) * 32];
    short* Al1 = &As[1][(w << 5) * 32];
    short* Bl1 = &Bs[1][(w << 5) * 32];

    f4v acc[4][4];
#pragma unroll
    for (int i = 0; i < 4; ++i)
#pragma unroll
        for (int j = 0; j < 4; ++j) acc[i][j] = (f4v){0.f, 0.f, 0.f, 0.f};

    auto stage = [&](int buf, int k0) {
        size_t kb = (size_t)k0 * 2;
        short* Al = buf ? Al1 : Al0;
        short* Bl = buf ? Bl1 : Bl0;
        GLOAD16(Ag + kb,           Al);
        GLOAD16(Ag + kb + rowskip, Al + 16 * 32);
        GLOAD16(Bg + kb,           Bl);
        GLOAD16(Bg + kb + rowskip, Bl + 16 * 32);
    };

    stage(0, 0);
    int cur = 0;
    int row16 = lane & 15, kg = (lane >> 4) << 3;
    for (int k0 = 0; k0 < K; k0 += 32) {
        __syncthreads();
        if (k0 + 32 < K) stage(cur ^ 1, k0 + 32);
        const short* Ab = As[cur];
        const short* Bb = Bs[cur];
        bf8v af[4], bfv[4];
#pragma unroll
        for (int fm = 0; fm < 4; ++fm)
            af[fm] = *(const bf8v*)&Ab[(wm + (fm << 4) + row16) * 32 + kg];
#pragma unroll
        for (int fn = 0; fn < 4; ++fn)
            bfv[fn] = *(const bf8v*)&Bb[(wn + (fn << 4) + row16) * 32 + kg];
#pragma unroll
        for (int fm = 0; fm < 4; ++fm)
#pragma unroll
            for (int fn = 0; fn < 4; ++fn)
                acc[fm][fn] = __builtin_amdgcn_mfma_f32_16x16x32_bf16(
                    af[fm], bfv[fn], acc[fm][fn], 0, 0, 0);
        cur ^= 1;
    }

    float gate = (EPI == 1) ? *gatep : 0.f;
    int rbase = m0 + wm + ((lane >> 4) << 2);
#pragma unroll
    for (int fn = 0; fn < 4; ++fn) {
        int col = n0 + wn + (fn << 4) + (lane & 15);
        if (col >= N) continue;
        float bc = bias[col];
        int dst = col;
        if (EPI == 2) {
            int hh = col / 129, q = col - hh * 129;
            if (q == 0) continue;          // dt handled by separate GEMM
            dst = hh * 128 + q - 1;
        }
#pragma unroll
        for (int fm = 0; fm < 4; ++fm) {
#pragma unroll
            for (int r = 0; r < 4; ++r) {
                int row = rbase + (fm << 4) + r;
                float v = acc[fm][fn][r] + bc;
                if (EPI == 1) {
                    v = resid[(size_t)row * N + col] + clampf(v, -100.f, 100.f) * gate;
                    st1(&C[(size_t)row * N + col], v);
                } else if (EPI == 2) {
                    st1(&C[(size_t)row * XPS + dst], v);
                } else {
                    st1(&C[(size_t)row * N + col], v);
                }
            }
        }
    }
}

// ---------------------------------------------------------------- conv+SiLU (batch-local, 8 ch x 4 rows/thread)
__global__ __launch_bounds__(192) void k_conv4(const bf16* __restrict__ x,
                                               const float* __restrict__ cw,
                                               const float* __restrict__ cb,
                                               bf16* __restrict__ xc) {
    int c0 = threadIdx.x * 8;
    int r0 = blockIdx.x * 4;             // rows r0..r0+3 (batch-local)
    bf8v xr[7];
    const bf8v z8 = (bf8v){0, 0, 0, 0, 0, 0, 0, 0};
#pragma unroll
    for (int j = 0; j < 7; ++j) {
        int rr = r0 - 3 + j;
        xr[j] = (rr >= 0) ? *(const bf8v*)(const void*)(x + (size_t)rr * DINNER + c0) : z8;
    }
    float wk[4][8], cbv[8];
#pragma unroll
    for (int j = 0; j < 8; ++j) {
        cbv[j] = cb[c0 + j];
#pragma unroll
        for (int k = 0; k < 4; ++k) wk[k][j] = cw[(c0 + j) * 4 + k];
    }
#pragma unroll
    for (int i = 0; i < 4; ++i) {
        bf8v o;
#pragma unroll
        for (int j = 0; j < 8; ++j) {
            float a = cbv[j];
#pragma unroll
            for (int k = 0; k < 4; ++k) a += wk[k][j] * bs2f(xr[i + k][j]);
            o[j] = f2bs(a / (1.f + expf(-a)));
        }
        *(bf8v*)(xc + (size_t)(r0 + i) * DINNER + c0) = o;
    }
}

// ---------------------------------------------------------------- per-(t,h): A value, 1/||B||, 1/||C||
__global__ __launch_bounds__(256) void k_prep(const bf16* __restrict__ xp,
                                              const bf16* __restrict__ dtb,
                                              const float* __restrict__ A_log,
                                              float* __restrict__ Aarr,
                                              float* __restrict__ invB,
                                              float* __restrict__ invC) {
    int wv = threadIdx.x >> 6, lane = threadIdx.x & 63;
    int idx = blockIdx.x * 4 + wv;
    int t = idx / 24, h = idx - t * 24;
    const bf16* base = xp + (size_t)t * XPS + h * 128;
    float b = bf2f(base[lane]), c = bf2f(base[64 + lane]);
    float sb = b * b, sc = c * c;
    for (int off = 32; off; off >>= 1) {
        sb += __shfl_xor(sb, off, 64);
        sc += __shfl_xor(sc, off, 64);
    }
    if (lane == 0) {
        invB[idx] = 1.f / fmaxf(sqrtf(sb), 1e-12f);
        invC[idx] = 1.f / fmaxf(sqrtf(sc), 1e-12f);
        float dt = clampf(bf2f(dtb[idx]), -10.f, 10.f);
        float dts = clampf(log1pf(expf(dt)), 0.01f, 10.f);
        float A = clampf(A_log[h], -2.3f, -0.01f) * dts;
        Aarr[idx] = clampf(A, -20.f, -0.001f);
    }
}

// ---------------------------------------------------------------- surprise (vectorized staging)
__global__ __launch_bounds__(256) void k_surprise_all(const bf16* __restrict__ xp,
                                                      const bf16* __restrict__ xc,
                                                      const float* __restrict__ invB,
                                                      float* __restrict__ cs) {
    int g = blockIdx.x;                 // 0..6143
    int cg = g / 24, h = g - cg * 24;   // cg: global chunk 0..255
    int b = cg >> 7, nl = cg & 127;
    int t0 = cg * 64;
    size_t cs_idx = (size_t)(b * 24 + h) * 128 + nl;
    __shared__ short Ws[64 * 72];   // B^T [s][c]
    __shared__ short Xt[64 * 72];   // X^T [d][c]
    int tid = threadIdx.x;
#pragma unroll
    for (int half = 0; half < 2; ++half) {
        int tau = tid + half * 256;
        int c = tau >> 3, s0 = (tau & 7) << 3;
        int t = t0 + c;
        float ib = invB[t * 24 + h];
        bf8v Bv = *(const bf8v*)(const void*)(xp + (size_t)t * XPS + h * 128 + s0);
        bf8v Xv = *(const bf8v*)(const void*)(xc + (size_t)t * DINNER + h * 64 + s0);
#pragma unroll
        for (int u = 0; u < 8; ++u) {
            Ws[(s0 + u) * 72 + c] = f2bs(bs2f(Bv[u]) * ib);
            Xt[(s0 + u) * 72 + c] = Xv[u];
        }
    }
    __syncthreads();
    int w = tid >> 6, lane = tid & 63;
    int r16 = lane & 15, kq = (lane >> 4) << 3;
    int strip = w << 4;
    f4v acc[4];
#pragma unroll
    for (int dt = 0; dt < 4; ++dt) acc[dt] = (f4v){0.f, 0.f, 0.f, 0.f};
#pragma unroll
    for (int ks = 0; ks < 2; ++ks) {
        bf8v af = *(const bf8v*)&Ws[(strip + r16) * 72 + ks * 32 + kq];
#pragma unroll
        for (int dt = 0; dt < 4; ++dt) {
            bf8v bf_ = *(const bf8v*)&Xt[((dt << 4) + r16) * 72 + ks * 32 + kq];
            acc[dt] = __builtin_amdgcn_mfma_f32_16x16x32_bf16(af, bf_, acc[dt], 0, 0, 0);
        }
    }
    float ss = 0.f;
#pragma unroll
    for (int dt = 0; dt < 4; ++dt)
#pragma unroll
        for (int r = 0; r < 4; ++r) ss += acc[dt][r] * acc[dt][r];
    for (int off = 32; off; off >>= 1) ss += __shfl_xor(ss, off, 64);
    __shared__ float ws4[4];
    if (lane == 0) ws4[w] = ss;
    __syncthreads();
    if (tid == 0) cs[cs_idx] = (ws4[0] + ws4[1] + ws4[2] + ws4[3]) * (1.f / 4096.f);
}

// ---------------------------------------------------------------- per-head EMA + alpha
__global__ __launch_bounds__(256) void k_alpha(const float* __restrict__ cs,
                                               const float* __restrict__ ema0,
                                               const float* __restrict__ l2ab,
                                               const float* __restrict__ l2b,
                                               float* __restrict__ alpha) {
    int h = blockIdx.x, tid = threadIdx.x;
    int b = tid >> 7, n = tid & 127;
    int gi = (b * 24 + h) * 128 + n;
    float v = cs[gi];
    float s = v;
    for (int off = 32; off; off >>= 1) s += __shfl_xor(s, off, 64);
    __shared__ float ws4[4];
    int lane = tid & 63, wv = tid >> 6;
    if (lane == 0) ws4[wv] = s;
    __syncthreads();
    float total = ws4[0] + ws4[1] + ws4[2] + ws4[3];
    float ema = 0.99f * ema0[h] + 0.01f * (total * (1.f / 256.f));
    float ab = 1.f - exp2f(clampf(l2ab[h], -3.32f, -0.015f));
    float beta = exp2f(clampf(l2b[h], -2.f, 2.f));
    float nz = v / (ema + 1e-6f);
    float boost = fmaxf(tanhf(beta * nz), 0.f);
    alpha[gi] = clampf(ab + (1.f - ab) * boost, 0.01f, 0.999f);
}

// ---------------------------------------------------------------- fused intra+hchunk (batch-local)
__global__ __launch_bounds__(256) void k_chunk(const bf16* __restrict__ xp,
                                               const bf16* __restrict__ xc,
                                               const float* __restrict__ invB,
                                               const float* __restrict__ invC,
                                               const float* __restrict__ Aarr,
                                               const float* __restrict__ alpha,
                                               bf16* __restrict__ ybuf,
                                               bf16* __restrict__ hf,
                                               float* __restrict__ dchunk,
                                               int b) {
    int g = blockIdx.x;                  // h*128 + nl
    int h = g >> 7, nl = g & 127;
    int t0 = nl * 64;                    // batch-local token
    size_t gidx = (size_t)(b * 24 + h) * 128 + nl;
    size_t hbase = (size_t)g * 4096;
    float alp = alpha[gidx];
    __shared__ short Cs[64 * 72];   // C rows [i][s]; later M [i][j]
    __shared__ short Bs[64 * 72];   // B rows [j][s]
    __shared__ short Ws[64 * 72];   // (dte·B)^T [s][c]
    __shared__ short Xt[64 * 72];   // X^T [d][c]
    __shared__ float Acs[64];
    __shared__ float dte[64];
    int tid = threadIdx.x;
    if (tid < 64) {
        float a = Aarr[(size_t)(t0 + tid) * 24 + h] * (1.f - alp);
        for (int off = 1; off < 64; off <<= 1) {
            float u = __shfl_up(a, off, 64);
            if (tid >= off) a += u;
        }
        Acs[tid] = a;
        float total = __shfl(a, 63, 64);
        dte[tid] = expf(total - a);
        if (tid == 0) dchunk[gidx] = expf(total);
    }
    __syncthreads();
#pragma unroll
    for (int half = 0; half < 2; ++half) {
        int tau = tid + half * 256;
        int c = tau >> 3, s0 = (tau & 7) << 3;
        int t = t0 + c;
        const bf16* bp = xp + (size_t)t * XPS + h * 128;
        float ib = invB[t * 24 + h], ic2 = invC[t * 24 + h];
        float dc = dte[c];
        bf8v Bv = *(const bf8v*)(const void*)(bp + s0);
        bf8v Cv = *(const bf8v*)(const void*)(bp + 64 + s0);
        bf8v Xv = *(const bf8v*)(const void*)(xc + (size_t)t * DINNER + h * 64 + s0);
        bf8v Bsc, Csc;
#pragma unroll
        for (int u = 0; u < 8; ++u) {
            float bv = bs2f(Bv[u]) * ib;
            Bsc[u] = f2bs(bv);
            Csc[u] = f2bs(bs2f(Cv[u]) * ic2);
            Ws[(s0 + u) * 72 + c] = f2bs(bv * dc);
            Xt[(s0 + u) * 72 + c] = Xv[u];
        }
        *(bf8v*)&Bs[c * 72 + s0] = Bsc;
        *(bf8v*)&Cs[c * 72 + s0] = Csc;
    }
    __syncthreads();
    int w = tid >> 6, lane = tid & 63;
    int r16 = lane & 15, kq = (lane >> 4) << 3;
    int strip = w << 4;
    f4v acb[4], ach[4];
#pragma unroll
    for (int jt = 0; jt < 4; ++jt) {
        acb[jt] = (f4v){0.f, 0.f, 0.f, 0.f};
        ach[jt] = (f4v){0.f, 0.f, 0.f, 0.f};
    }
#pragma unroll
    for (int ks = 0; ks < 2; ++ks) {
        bf8v afc = *(const bf8v*)&Cs[(strip + r16) * 72 + ks * 32 + kq];
        bf8v afw = *(const bf8v*)&Ws[(strip + r16) * 72 + ks * 32 + kq];
#pragma unroll
        for (int jt = 0; jt < 4; ++jt) {
            bf8v bb = *(const bf8v*)&Bs[((jt << 4) + r16) * 72 + ks * 32 + kq];
            acb[jt] = __builtin_amdgcn_mfma_f32_16x16x32_bf16(afc, bb, acb[jt], 0, 0, 0);
            bf8v xx = *(const bf8v*)&Xt[((jt << 4) + r16) * 72 + ks * 32 + kq];
            ach[jt] = __builtin_amdgcn_mfma_f32_16x16x32_bf16(afw, xx, ach[jt], 0, 0, 0);
        }
    }
    int rbase = strip + ((lane >> 4) << 2);
#pragma unroll
    for (int dt = 0; dt < 4; ++dt) {
        int d = (dt << 4) + r16;
#pragma unroll
        for (int r = 0; r < 4; ++r)
            hf[hbase + (size_t)(rbase + r) * 64 + d] = f2bf(ach[dt][r]);
    }
    __syncthreads();
    short* Ms = Cs;
#pragma unroll
    for (int jt = 0; jt < 4; ++jt) {
        int j = (jt << 4) + r16;
        float aj = Acs[j];
#pragma unroll
        for (int r = 0; r < 4; ++r) {
            int i = rbase + r;
            float m = (j <= i) ? expf(Acs[i] - aj) * acb[jt][r] : 0.f;
            Ms[i * 72 + j] = f2bs(m);
        }
    }
    __syncthreads();
    f4v acy[4];
#pragma unroll
    for (int dt = 0; dt < 4; ++dt) acy[dt] = (f4v){0.f, 0.f, 0.f, 0.f};
#pragma unroll
    for (int ks = 0; ks < 2; ++ks) {
        bf8v afm = *(const bf8v*)&Ms[(strip + r16) * 72 + ks * 32 + kq];
#pragma unroll
        for (int dt = 0; dt < 4; ++dt) {
            bf8v xx = *(const bf8v*)&Xt[((dt << 4) + r16) * 72 + ks * 32 + kq];
            acy[dt] = __builtin_amdgcn_mfma_f32_16x16x32_bf16(afm, xx, acy[dt], 0, 0, 0);
        }
    }
#pragma unroll
    for (int dt = 0; dt < 4; ++dt) {
        int d = (dt << 4) + r16;
#pragma unroll
        for (int r = 0; r < 4; ++r) {
            int i = rbase + r;
            ybuf[(size_t)(t0 + i) * DINNER + h * 64 + d] = f2bf(acy[dt][r]);
        }
    }
}

// ---------------------------------------------------------------- chunk scan (batch-local, depth-4 pipeline)
__global__ __launch_bounds__(256) void k_scan(bf16* __restrict__ hf,
                                              const float* __restrict__ dchunk,
                                              int b) {
    int h = blockIdx.x >> 4;                         // 0..23
    int e = ((blockIdx.x & 15) << 8) + threadIdx.x;  // 0..4095
    size_t abase = (size_t)h * 128 * 4096 + e;
    const float* dcp = dchunk + (size_t)(b * 24 + h) * 128;
    float c = 0.f;
    float v0 = bf2f(hf[abase]);
    float v1 = bf2f(hf[abase + 1 * 4096]);
    float v2 = bf2f(hf[abase + 2 * 4096]);
    float v3 = bf2f(hf[abase + 3 * 4096]);
    for (int nl = 0; nl < 128; nl += 4) {
        float p0 = (nl + 4 < 128) ? bf2f(hf[abase + (size_t)(nl + 4) * 4096]) : 0.f;
        float p1 = (nl + 5 < 128) ? bf2f(hf[abase + (size_t)(nl + 5) * 4096]) : 0.f;
        float p2 = (nl + 6 < 128) ? bf2f(hf[abase + (size_t)(nl + 6) * 4096]) : 0.f;
        float p3 = (nl + 7 < 128) ? bf2f(hf[abase + (size_t)(nl + 7) * 4096]) : 0.f;
        hf[abase + (size_t)nl * 4096] = f2bf(c);
        c = dcp[nl] * c + v0;
        hf[abase + (size_t)(nl + 1) * 4096] = f2bf(c);
        c = dcp[nl + 1] * c + v1;
        hf[abase + (size_t)(nl + 2) * 4096] = f2bf(c);
        c = dcp[nl + 2] * c + v2;
        hf[abase + (size_t)(nl + 3) * 4096] = f2bf(c);
        c = dcp[nl + 3] * c + v3;
        v0 = p0; v1 = p1; v2 = p2; v3 = p3;
    }
}

// ---------------------------------------------------------------- Y_inter + gate (batch-local)
__global__ __launch_bounds__(256) void k_inter(const bf16* __restrict__ xp,
                                               const float* __restrict__ invC,
                                               const float* __restrict__ Aarr,
                                               const float* __restrict__ alpha,
                                               const bf16* __restrict__ hf,
                                               const bf16* __restrict__ zbuf,
                                               bf16* __restrict__ ybuf,
                                               int b) {
    int g = blockIdx.x;                  // h*128 + nl
    int h = g >> 7, nl = g & 127;
    int t0 = nl * 64;
    size_t gidx = (size_t)(b * 24 + h) * 128 + nl;
    size_t hbase = (size_t)g * 4096;
    float alp = alpha[gidx];
    __shared__ short Cs[64 * 72];
    __shared__ short Ht[64 * 72];
    __shared__ float dfs[64];
    int tid = threadIdx.x;
    if (tid < 64) {
        float a = Aarr[(size_t)(t0 + tid) * 24 + h] * (1.f - alp);
        for (int off = 1; off < 64; off <<= 1) {
            float u = __shfl_up(a, off, 64);
            if (tid >= off) a += u;
        }
        dfs[tid] = expf(a);
    }
#pragma unroll
    for (int half = 0; half < 2; ++half) {
        int tau = tid + half * 256;
        int c = tau >> 3, s0 = (tau & 7) << 3;
        int t = t0 + c;
        float ic2 = invC[t * 24 + h];
        bf8v Cv = *(const bf8v*)(const void*)(xp + (size_t)t * XPS + h * 128 + 64 + s0);
        bf8v Hv = *(const bf8v*)(const void*)(hf + hbase + (size_t)c * 64 + s0);
        bf8v Csc;
#pragma unroll
        for (int u = 0; u < 8; ++u) {
            Csc[u] = f2bs(bs2f(Cv[u]) * ic2);
            Ht[(s0 + u) * 72 + c] = Hv[u];
        }
        *(bf8v*)&Cs[c * 72 + s0] = Csc;
    }
    __syncthreads();
    int w = tid >> 6, lane = tid & 63;
    int r16 = lane & 15, kq = (lane >> 4) << 3;
    int strip = w << 4;
    f4v acc[4];
#pragma unroll
    for (int dt = 0; dt < 4; ++dt) acc[dt] = (f4v){0.f, 0.f, 0.f, 0.f};
#pragma unroll
    for (int ks = 0; ks < 2; ++ks) {
        bf8v af = *(const bf8v*)&Cs[(strip + r16) * 72 + ks * 32 + kq];
#pragma unroll
        for (int dt = 0; dt < 4; ++dt) {
            bf8v hfr = *(const bf8v*)&Ht[((dt << 4) + r16) * 72 + ks * 32 + kq];
            acc[dt] = __builtin_amdgcn_mfma_f32_16x16x32_bf16(af, hfr, acc[dt], 0, 0, 0);
        }
    }
    int ibase = strip + ((lane >> 4) << 2);
#pragma unroll
    for (int dt = 0; dt < 4; ++dt) {
        int d = (dt << 4) + r16;
#pragma unroll
        for (int r = 0; r < 4; ++r) {
            int i = ibase + r;
            float df = dfs[i];
            size_t yoff = (size_t)(t0 + i) * DINNER + h * 64 + d;
            float Y = clampf(bf2f(ybuf[yoff]) + df * acc[dt][r], -100.f, 100.f);
            float zz = bf2f(zbuf[yoff]);
            ybuf[yoff] = f2bf(Y / (1.f + expf(-zz)));
        }
    }
}

// ---------------------------------------------------------------- launch
extern "C" void kernel_launch(void* const* d_in, const int* in_sizes, int n_in,
                              void* d_out, int out_size, void* d_ws, size_t ws_size,
                              hipStream_t stream) {
    const float* hs     = (const float*)d_in[0];
    const float* norm_w = (const float*)d_in[1];
    const float* w1     = (const float*)d_in[2];
    const float* b1     = (const float*)d_in[3];
    const float* cw     = (const float*)d_in[4];
    const float* cbias  = (const float*)d_in[5];
    const float* w2     = (const float*)d_in[6];
    const float* b2     = (const float*)d_in[7];
    const float* A_log  = (const float*)d_in[8];
    const float* l2ab   = (const float*)d_in[9];
    const float* l2b    = (const float*)d_in[10];
    const float* ema0   = (const float*)d_in[11];
    const float* w3     = (const float*)d_in[12];
    const float* b3     = (const float*)d_in[13];
    const float* rg     = (const float*)d_in[14];
    float* out = (float*)d_out;

    // footprint ~186.5 MB; proven ws_size >= ~199.1 MB (R10 layout ran)
    char* base = (char*)d_ws;
    size_t off = 0;
    auto alloc = [&](size_t bytes) -> void* {
        void* p = base + off;
        off += (bytes + 255) & ~(size_t)255;
        return p;
    };
    bf16* w1bf  = (bf16*)alloc((size_t)2 * DINNER * DMODEL * 2);
    bf16* w2bf  = (bf16*)alloc((size_t)NPROJP * DINNER * 2);
    bf16* w3bf  = (bf16*)alloc((size_t)DMODEL * DINNER * 2);
    bf16* wdt   = (bf16*)alloc((size_t)128 * DINNER * 2);
    float* bdt  = (float*)alloc((size_t)128 * 4);
    bf16* xnb   = (bf16*)alloc((size_t)BT * DMODEL * 2);         // per-batch rmsnorm out
    bf16* ybuf  = (bf16*)alloc((size_t)BT * DINNER * 2);         // per-batch Y / pre-conv x
    bf16* hf    = (bf16*)alloc((size_t)NHEADS * 128 * 4096 * 2); // per-batch chunk states
    bf16* dtb   = (bf16*)alloc((size_t)NTOK * 24 * 2);
    float* cs   = (float*)alloc((size_t)6144 * 4);
    float* alp  = (float*)alloc((size_t)6144 * 4);
    float* dch  = (float*)alloc((size_t)6144 * 4);
    bf16* xp    = (bf16*)alloc((size_t)NTOK * XPS * 2);
    float* Aarr = (float*)alloc((size_t)NTOK * 24 * 4);
    float* invB = (float*)alloc((size_t)NTOK * 24 * 4);
    float* invC = (float*)alloc((size_t)NTOK * 24 * 4);
    bf16* xbuf  = ybuf;                    // pre-conv x aliases ybuf
    bf16* xc_all = (bf16*)d_out;           // xc for all tokens lives in d_out

    {
        int n1 = 2 * DINNER * DMODEL / 4, n2 = NPROJ * DINNER / 4, n3 = DMODEL * DINNER / 4;
        k_cvt<<<(n1 + 255) / 256, 256, 0, stream>>>(w1, w1bf, n1);
        k_cvt<<<(n2 + 255) / 256, 256, 0, stream>>>(w2, w2bf, n2);
        k_cvt<<<(n3 + 255) / 256, 256, 0, stream>>>(w3, w3bf, n3);
        int nz = (NPROJP - NPROJ) * DINNER;
        k_zero<<<(nz + 255) / 256, 256, 0, stream>>>(w2bf + (size_t)NPROJ * DINNER, nz);
        k_wdt<<<(128 * DINNER + 255) / 256, 256, 0, stream>>>(w2, b2, wdt, bdt);
    }

    const dim3 gXb(DINNER / 128, BT / 128);          // 12 x 64
    const dim3 gOb(DMODEL / 128, BT / 128);          // 6 x 64
    const dim3 gPall(NPROJP / 128, NTOK / 128);      // 25 x 128
    const dim3 gDt(1, NTOK / 128);                   // 1 x 128 (dt GEMM, N=24)

    // ---------------- phase 1: front-end per batch; xc cached into d_out
    for (int bt = 0; bt < 2; ++bt) {
        size_t t0 = (size_t)bt * BT;
        k_rmsnorm<<<BT, 256, 0, stream>>>(hs + t0 * DMODEL, norm_w, xnb);
        k_mgemm<bf16, 0><<<gXb, 256, 0, stream>>>(xnb, w1bf, b1, xbuf,
                                                  BT, DINNER, DMODEL, nullptr, nullptr);
        k_conv4<<<BT / 4, 192, 0, stream>>>(xbuf, cw, cbias, xc_all + t0 * DINNER);
    }
    // x_proj over all tokens (B/C to xp; dt via separate skinny GEMM)
    k_mgemm<bf16, 2><<<gPall, 256, 0, stream>>>(xc_all, w2bf, b2, xp,
                                                NTOK, NPROJ, DINNER, nullptr, nullptr);
    k_mgemm<bf16, 0><<<gDt, 256, 0, stream>>>(xc_all, wdt, bdt, dtb,
                                              NTOK, 24, DINNER, nullptr, nullptr);
    k_prep<<<NTOK * 24 / 4, 256, 0, stream>>>(xp, dtb, A_log, Aarr, invB, invC);
    k_surprise_all<<<6144, 256, 0, stream>>>(xp, xc_all, invB, cs);
    k_alpha<<<24, 256, 0, stream>>>(cs, ema0, l2ab, l2b, alp);

    // ---------------- phase 2: batch 1 first (xnb still holds batch-1 xn), then batch 0
    for (int pass = 0; pass < 2; ++pass) {
        int bt = 1 - pass;
        size_t t0 = (size_t)bt * BT;
        bf16* xc = xc_all + t0 * DINNER;
        bf16* zseg = xc;                   // z overwrites dead xc region of d_out
        const bf16* xpS = xp + t0 * XPS;
        const float* AarrS = Aarr + t0 * 24;
        const float* invBS = invB + t0 * 24;
        const float* invCS = invC + t0 * 24;
        k_chunk<<<NHEADS * 128, 256, 0, stream>>>(xpS, xc, invBS, invCS, AarrS, alp,
                                                  ybuf, hf, dch, bt);
        if (bt == 0)   // batch-1 xn persists from phase 1; batch 0 must recompute
            k_rmsnorm<<<BT, 256, 0, stream>>>(hs + t0 * DMODEL, norm_w, xnb);
        k_mgemm<bf16, 0><<<gXb, 256, 0, stream>>>(xnb, w1bf + (size_t)DINNER * DMODEL,
                                                  b1 + DINNER, zseg,
                                                  BT, DINNER, DMODEL, nullptr, nullptr);
        k_scan<<<384, 256, 0, stream>>>(hf, dch, bt);
        k_inter<<<NHEADS * 128, 256, 0, stream>>>(xpS, invCS, AarrS, alp, hf, zseg, ybuf, bt);
        k_mgemm<float, 1><<<gOb, 256, 0, stream>>>(ybuf, w3bf, b3, out + t0 * DMODEL,
                                                   BT, DMODEL, DINNER,
                                                   hs + t0 * DMODEL, rg);
    }
}

// Round 16
// 778.040 us; speedup vs baseline: 1.1979x; 1.0078x over previous
//
#include <hip/hip_runtime.h>
#include <hip/hip_bf16.h>
#include <cstdint>
#include <cstddef>

#define L_SEQ   8192
#define DMODEL  768
#define NHEADS  24
#define DINNER  1536
#define NPROJ   3096      /* logical proj cols: 24 * 129 */
#define NPROJP  3200      /* padded weight rows for gload_lds */
#define XPS     3072      /* xp row stride: 24 heads * 128 (B@0..63, C@64..127) */
#define NTOK    16384
#define BT      8192      /* tokens per batch */
#define RMS_EPS 1.1920929e-07f

typedef __hip_bfloat16 bf16;
typedef __attribute__((ext_vector_type(8))) short bf8v;
typedef __attribute__((ext_vector_type(4))) float f4v;

__device__ __forceinline__ float clampf(float x, float lo, float hi) {
    return fminf(fmaxf(x, lo), hi);
}
__device__ __forceinline__ float bf2f(bf16 v) { return __bfloat162float(v); }
__device__ __forceinline__ bf16  f2bf(float v) { return __float2bfloat16(v); }
__device__ __forceinline__ short f2bs(float v) {
    bf16 b = __float2bfloat16(v);
    return *reinterpret_cast<short*>(&b);
}
__device__ __forceinline__ float bs2f(short v) {
    return __uint_as_float(((unsigned)(unsigned short)v) << 16);
}
__device__ __forceinline__ void st1(float* p, float v) { *p = v; }
__device__ __forceinline__ void st1(bf16* p, float v) { *p = f2bf(v); }
__device__ __forceinline__ void st4(bf16* p, float4 v) {
    p[0] = f2bf(v.x); p[1] = f2bf(v.y); p[2] = f2bf(v.z); p[3] = f2bf(v.w);
}

#define GLOAD16(gsrc, ldst) __builtin_amdgcn_global_load_lds( \
    (const __attribute__((address_space(1))) void*)(gsrc),    \
    (__attribute__((address_space(3))) void*)(ldst), 16, 0, 0)

// ---------------------------------------------------------------- weight cvt / zero / dt-slice
__global__ __launch_bounds__(256) void k_cvt(const float* __restrict__ s,
                                             bf16* __restrict__ d, int n4) {
    int i = blockIdx.x * 256 + threadIdx.x;
    if (i < n4) {
        float4 v = *(const float4*)&s[i * 4];
        st4(&d[i * 4], v);
    }
}
__global__ __launch_bounds__(256) void k_zero(bf16* __restrict__ d, int n) {
    int i = blockIdx.x * 256 + threadIdx.x;
    if (i < n) d[i] = f2bf(0.f);
}
__global__ __launch_bounds__(256) void k_wdt(const float* __restrict__ w2,
                                             const float* __restrict__ b2,
                                             bf16* __restrict__ wdt,
                                             float* __restrict__ bdt) {
    int i = blockIdx.x * 256 + threadIdx.x;
    if (i < 128 * DINNER) {
        int h = i / DINNER, c = i - h * DINNER;
        wdt[i] = f2bf(h < 24 ? w2[(size_t)(h * 129) * DINNER + c] : 0.f);
    }
    if (i < 128) bdt[i] = (i < 24) ? b2[i * 129] : 0.f;
}

// ---------------------------------------------------------------- RMSNorm (f32 in, bf16 out)
__global__ __launch_bounds__(256) void k_rmsnorm(const float* __restrict__ hs,
                                                 const float* __restrict__ w,
                                                 bf16* __restrict__ xn) {
    int t = blockIdx.x;
    const float* p = hs + (size_t)t * DMODEL;
    float s = 0.f;
    for (int i = threadIdx.x; i < DMODEL; i += 256) { float v = p[i]; s += v * v; }
    for (int off = 32; off; off >>= 1) s += __shfl_xor(s, off, 64);
    __shared__ float ws4[4];
    int lane = threadIdx.x & 63, wv = threadIdx.x >> 6;
    if (lane == 0) ws4[wv] = s;
    __syncthreads();
    s = ws4[0] + ws4[1] + ws4[2] + ws4[3];
    float r = 1.0f / sqrtf(s * (1.0f / DMODEL) + RMS_EPS);
    bf16* o = xn + (size_t)t * DMODEL;
    for (int i = threadIdx.x; i < DMODEL; i += 256) o[i] = f2bf(p[i] * r * w[i]);
}

// ---------------------------------------------------------------- MFMA GEMM 128x128 (4 waves) — out/dt shapes
// EPI 0: plain   EPI 1: +resid/clip/gate (f32 out)
template <typename TC, int EPI>
__global__ __launch_bounds__(256) void k_mgemm(const bf16* __restrict__ A,
                                               const bf16* __restrict__ B,
                                               const float* __restrict__ bias,
                                               TC* __restrict__ C,
                                               int M, int N, int K,
                                               const float* __restrict__ resid,
                                               const float* __restrict__ gatep) {
    __shared__ short As[2][128 * 32];
    __shared__ short Bs[2][128 * 32];
    int tid = threadIdx.x;
    int lane = tid & 63, w = tid >> 6;

    int gx = gridDim.x, gy = gridDim.y;
    int bid = blockIdx.y * gx + blockIdx.x;
    int xcd = bid & 7, idx = bid >> 3;
    int bys = gy >> 3;
    int gby = bys < 8 ? bys : 8;
    int sg  = idx / (gx * gby);
    int rem = idx - sg * (gx * gby);
    int bx  = rem / gby;
    int byl = rem - bx * gby;
    int by  = xcd * bys + sg * gby + byl;
    int m0 = by * 128, n0 = bx * 128;

    int wm = (w >> 1) << 6, wn = (w & 1) << 6;

    const size_t rowskip = (size_t)16 * K * 2;
    const char* Ag = (const char*)(A + (size_t)(m0 + (w << 5) + (lane >> 2)) * K) + (lane & 3) * 16;
    const char* Bg = (const char*)(B + (size_t)(n0 + (w << 5) + (lane >> 2)) * K) + (lane & 3) * 16;
    short* Al0 = &As[0][(w << 5) * 32];
    short* Bl0 = &Bs[0][(w << 5) * 32];
    short* Al1 = &As[1][(w << 5) * 32];
    short* Bl1 = &Bs[1][(w << 5) * 32];

    f4v acc[4][4];
#pragma unroll
    for (int i = 0; i < 4; ++i)
#pragma unroll
        for (int j = 0; j < 4; ++j) acc[i][j] = (f4v){0.f, 0.f, 0.f, 0.f};

    auto stage = [&](int buf, int k0) {
        size_t kb = (size_t)k0 * 2;
        short* Al = buf ? Al1 : Al0;
        short* Bl = buf ? Bl1 : Bl0;
        GLOAD16(Ag + kb,           Al);
        GLOAD16(Ag + kb + rowskip, Al + 16 * 32);
        GLOAD16(Bg + kb,           Bl);
        GLOAD16(Bg + kb + rowskip, Bl + 16 * 32);
    };

    stage(0, 0);
    int cur = 0;
    int row16 = lane & 15, kg = (lane >> 4) << 3;
    for (int k0 = 0; k0 < K; k0 += 32) {
        __syncthreads();
        if (k0 + 32 < K) stage(cur ^ 1, k0 + 32);
        const short* Ab = As[cur];
        const short* Bb = Bs[cur];
        bf8v af[4], bfv[4];
#pragma unroll
        for (int fm = 0; fm < 4; ++fm)
            af[fm] = *(const bf8v*)&Ab[(wm + (fm << 4) + row16) * 32 + kg];
#pragma unroll
        for (int fn = 0; fn < 4; ++fn)
            bfv[fn] = *(const bf8v*)&Bb[(wn + (fn << 4) + row16) * 32 + kg];
#pragma unroll
        for (int fm = 0; fm < 4; ++fm)
#pragma unroll
            for (int fn = 0; fn < 4; ++fn)
                acc[fm][fn] = __builtin_amdgcn_mfma_f32_16x16x32_bf16(
                    af[fm], bfv[fn], acc[fm][fn], 0, 0, 0);
        cur ^= 1;
    }

    float gate = (EPI == 1) ? *gatep : 0.f;
    int rbase = m0 + wm + ((lane >> 4) << 2);
#pragma unroll
    for (int fn = 0; fn < 4; ++fn) {
        int col = n0 + wn + (fn << 4) + (lane & 15);
        if (col >= N) continue;
        float bc = bias[col];
#pragma unroll
        for (int fm = 0; fm < 4; ++fm) {
#pragma unroll
            for (int r = 0; r < 4; ++r) {
                int row = rbase + (fm << 4) + r;
                float v = acc[fm][fn][r] + bc;
                if (EPI == 1)
                    v = resid[(size_t)row * N + col] + clampf(v, -100.f, 100.f) * gate;
                st1(&C[(size_t)row * N + col], v);
            }
        }
    }
}

// ---------------------------------------------------------------- MFMA GEMM 256x128 (8 waves, 512 thr) — xp & x/z shapes
// Same 2-barrier dbuf structure; A rows 0..255, B rows 256..383 in one LDS pool.
// EPI 0: plain   EPI 2: xp store (skip q==0; dst = h*128+q-1)
template <typename TC, int EPI>
__global__ __launch_bounds__(512) void k_mgemm2(const bf16* __restrict__ A,
                                                const bf16* __restrict__ B,
                                                const float* __restrict__ bias,
                                                TC* __restrict__ C,
                                                int M, int N, int K) {
    __shared__ short AB[2][384 * 32];
    int tid = threadIdx.x;
    int lane = tid & 63, w = tid >> 6;

    int gx = gridDim.x, gy = gridDim.y;
    int bid = blockIdx.y * gx + blockIdx.x;
    int xcd = bid & 7, idx = bid >> 3;
    int bys = gy >> 3;                      // M-tile rows per XCD
    int gby = bys < 4 ? bys : 4;            // stripe: 4x256 rows = 3.1 MB, L2-fits
    int sg  = idx / (gx * gby);
    int rem = idx - sg * (gx * gby);
    int bx  = rem / gby;
    int byl = rem - bx * gby;
    int by  = xcd * bys + sg * gby + byl;
    int m0 = by * 256, n0 = bx * 128;

    int wm = (w >> 1) << 6, wn = (w & 1) << 6;   // 4M x 2N waves -> 256x128

    // staging: 3 issues/thread; granule g = i*512 + tid -> row g>>2, colq g&3
    const bf16* gp[3];
#pragma unroll
    for (int i = 0; i < 3; ++i) {
        int g = i * 512 + tid;
        int row = g >> 2, cq = (g & 3) << 3;
        gp[i] = (row < 256 ? A + (size_t)(m0 + row) * K
                           : B + (size_t)(n0 + row - 256) * K) + cq;
    }

    f4v acc[4][4];
#pragma unroll
    for (int i = 0; i < 4; ++i)
#pragma unroll
        for (int j = 0; j < 4; ++j) acc[i][j] = (f4v){0.f, 0.f, 0.f, 0.f};

    auto stage = [&](int buf, int k0) {
#pragma unroll
        for (int i = 0; i < 3; ++i) {
            short* dst = &AB[buf][(i * 512 + (w << 6)) * 8];   // wave-uniform base
            GLOAD16((const char*)gp[i] + (size_t)k0 * 2, dst);
        }
    };

    stage(0, 0);
    int cur = 0;
    int row16 = lane & 15, kg = (lane >> 4) << 3;
    for (int k0 = 0; k0 < K; k0 += 32) {
        __syncthreads();
        if (k0 + 32 < K) stage(cur ^ 1, k0 + 32);
        const short* Ab = AB[cur];
        const short* Bb = AB[cur] + 256 * 32;
        bf8v af[4], bfv[4];
#pragma unroll
        for (int fm = 0; fm < 4; ++fm)
            af[fm] = *(const bf8v*)&Ab[(wm + (fm << 4) + row16) * 32 + kg];
#pragma unroll
        for (int fn = 0; fn < 4; ++fn)
            bfv[fn] = *(const bf8v*)&Bb[(wn + (fn << 4) + row16) * 32 + kg];
#pragma unroll
        for (int fm = 0; fm < 4; ++fm)
#pragma unroll
            for (int fn = 0; fn < 4; ++fn)
                acc[fm][fn] = __builtin_amdgcn_mfma_f32_16x16x32_bf16(
                    af[fm], bfv[fn], acc[fm][fn], 0, 0, 0);
        cur ^= 1;
    }

    int rbase = m0 + wm + ((lane >> 4) << 2);
#pragma unroll
    for (int fn = 0; fn < 4; ++fn) {
        int col = n0 + wn + (fn << 4) + (lane & 15);
        if (col >= N) continue;
        float bc = bias[col];
        int dst = col;
        if (EPI == 2) {
            int hh = col / 129, q = col - hh * 129;
            if (q == 0) continue;          // dt handled by separate GEMM
            dst = hh * 128 + q - 1;
        }
#pragma unroll
        for (int fm = 0; fm < 4; ++fm) {
#pragma unroll
            for (int r = 0; r < 4; ++r) {
                int row = rbase + (fm << 4) + r;
                float v = acc[fm][fn][r] + bc;
                if (EPI == 2) st1(&C[(size_t)row * XPS + dst], v);
                else          st1(&C[(size_t)row * N + col], v);
            }
        }
    }
}

// ---------------------------------------------------------------- conv+SiLU (batch-local, 8 ch x 4 rows/thread)
__global__ __launch_bounds__(192) void k_conv4(const bf16* __restrict__ x,
                                               const float* __restrict__ cw,
                                               const float* __restrict__ cb,
                                               bf16* __restrict__ xc) {
    int c0 = threadIdx.x * 8;
    int r0 = blockIdx.x * 4;
    bf8v xr[7];
    const bf8v z8 = (bf8v){0, 0, 0, 0, 0, 0, 0, 0};
#pragma unroll
    for (int j = 0; j < 7; ++j) {
        int rr = r0 - 3 + j;
        xr[j] = (rr >= 0) ? *(const bf8v*)(const void*)(x + (size_t)rr * DINNER + c0) : z8;
    }
    float wk[4][8], cbv[8];
#pragma unroll
    for (int j = 0; j < 8; ++j) {
        cbv[j] = cb[c0 + j];
#pragma unroll
        for (int k = 0; k < 4; ++k) wk[k][j] = cw[(c0 + j) * 4 + k];
    }
#pragma unroll
    for (int i = 0; i < 4; ++i) {
        bf8v o;
#pragma unroll
        for (int j = 0; j < 8; ++j) {
            float a = cbv[j];
#pragma unroll
            for (int k = 0; k < 4; ++k) a += wk[k][j] * bs2f(xr[i + k][j]);
            o[j] = f2bs(a / (1.f + expf(-a)));
        }
        *(bf8v*)(xc + (size_t)(r0 + i) * DINNER + c0) = o;
    }
}

// ---------------------------------------------------------------- per-(t,h): A value, 1/||B||, 1/||C||
__global__ __launch_bounds__(256) void k_prep(const bf16* __restrict__ xp,
                                              const bf16* __restrict__ dtb,
                                              const float* __restrict__ A_log,
                                              float* __restrict__ Aarr,
                                              float* __restrict__ invB,
                                              float* __restrict__ invC) {
    int wv = threadIdx.x >> 6, lane = threadIdx.x & 63;
    int idx = blockIdx.x * 4 + wv;
    int t = idx / 24, h = idx - t * 24;
    const bf16* base = xp + (size_t)t * XPS + h * 128;
    float b = bf2f(base[lane]), c = bf2f(base[64 + lane]);
    float sb = b * b, sc = c * c;
    for (int off = 32; off; off >>= 1) {
        sb += __shfl_xor(sb, off, 64);
        sc += __shfl_xor(sc, off, 64);
    }
    if (lane == 0) {
        invB[idx] = 1.f / fmaxf(sqrtf(sb), 1e-12f);
        invC[idx] = 1.f / fmaxf(sqrtf(sc), 1e-12f);
        float dt = clampf(bf2f(dtb[idx]), -10.f, 10.f);
        float dts = clampf(log1pf(expf(dt)), 0.01f, 10.f);
        float A = clampf(A_log[h], -2.3f, -0.01f) * dts;
        Aarr[idx] = clampf(A, -20.f, -0.001f);
    }
}

// ---------------------------------------------------------------- surprise (vectorized staging)
__global__ __launch_bounds__(256) void k_surprise_all(const bf16* __restrict__ xp,
                                                      const bf16* __restrict__ xc,
                                                      const float* __restrict__ invB,
                                                      float* __restrict__ cs) {
    int g = blockIdx.x;
    int cg = g / 24, h = g - cg * 24;
    int b = cg >> 7, nl = cg & 127;
    int t0 = cg * 64;
    size_t cs_idx = (size_t)(b * 24 + h) * 128 + nl;
    __shared__ short Ws[64 * 72];
    __shared__ short Xt[64 * 72];
    int tid = threadIdx.x;
#pragma unroll
    for (int half = 0; half < 2; ++half) {
        int tau = tid + half * 256;
        int c = tau >> 3, s0 = (tau & 7) << 3;
        int t = t0 + c;
        float ib = invB[t * 24 + h];
        bf8v Bv = *(const bf8v*)(const void*)(xp + (size_t)t * XPS + h * 128 + s0);
        bf8v Xv = *(const bf8v*)(const void*)(xc + (size_t)t * DINNER + h * 64 + s0);
#pragma unroll
        for (int u = 0; u < 8; ++u) {
            Ws[(s0 + u) * 72 + c] = f2bs(bs2f(Bv[u]) * ib);
            Xt[(s0 + u) * 72 + c] = Xv[u];
        }
    }
    __syncthreads();
    int w = tid >> 6, lane = tid & 63;
    int r16 = lane & 15, kq = (lane >> 4) << 3;
    int strip = w << 4;
    f4v acc[4];
#pragma unroll
    for (int dt = 0; dt < 4; ++dt) acc[dt] = (f4v){0.f, 0.f, 0.f, 0.f};
#pragma unroll
    for (int ks = 0; ks < 2; ++ks) {
        bf8v af = *(const bf8v*)&Ws[(strip + r16) * 72 + ks * 32 + kq];
#pragma unroll
        for (int dt = 0; dt < 4; ++dt) {
            bf8v bf_ = *(const bf8v*)&Xt[((dt << 4) + r16) * 72 + ks * 32 + kq];
            acc[dt] = __builtin_amdgcn_mfma_f32_16x16x32_bf16(af, bf_, acc[dt], 0, 0, 0);
        }
    }
    float ss = 0.f;
#pragma unroll
    for (int dt = 0; dt < 4; ++dt)
#pragma unroll
        for (int r = 0; r < 4; ++r) ss += acc[dt][r] * acc[dt][r];
    for (int off = 32; off; off >>= 1) ss += __shfl_xor(ss, off, 64);
    __shared__ float ws4[4];
    if (lane == 0) ws4[w] = ss;
    __syncthreads();
    if (tid == 0) cs[cs_idx] = (ws4[0] + ws4[1] + ws4[2] + ws4[3]) * (1.f / 4096.f);
}

// ---------------------------------------------------------------- per-head EMA + alpha
__global__ __launch_bounds__(256) void k_alpha(const float* __restrict__ cs,
                                               const float* __restrict__ ema0,
                                               const float* __restrict__ l2ab,
                                               const float* __restrict__ l2b,
                                               float* __restrict__ alpha) {
    int h = blockIdx.x, tid = threadIdx.x;
    int b = tid >> 7, n = tid & 127;
    int gi = (b * 24 + h) * 128 + n;
    float v = cs[gi];
    float s = v;
    for (int off = 32; off; off >>= 1) s += __shfl_xor(s, off, 64);
    __shared__ float ws4[4];
    int lane = tid & 63, wv = tid >> 6;
    if (lane == 0) ws4[wv] = s;
    __syncthreads();
    float total = ws4[0] + ws4[1] + ws4[2] + ws4[3];
    float ema = 0.99f * ema0[h] + 0.01f * (total * (1.f / 256.f));
    float ab = 1.f - exp2f(clampf(l2ab[h], -3.32f, -0.015f));
    float beta = exp2f(clampf(l2b[h], -2.f, 2.f));
    float nz = v / (ema + 1e-6f);
    float boost = fmaxf(tanhf(beta * nz), 0.f);
    alpha[gi] = clampf(ab + (1.f - ab) * boost, 0.01f, 0.999f);
}

// ---------------------------------------------------------------- fused intra+hchunk (batch-local)
__global__ __launch_bounds__(256) void k_chunk(const bf16* __restrict__ xp,
                                               const bf16* __restrict__ xc,
                                               const float* __restrict__ invB,
                                               const float* __restrict__ invC,
                                               const float* __restrict__ Aarr,
                                               const float* __restrict__ alpha,
                                               bf16* __restrict__ ybuf,
                                               bf16* __restrict__ hf,
                                               float* __restrict__ dchunk,
                                               int b) {
    int g = blockIdx.x;
    int h = g >> 7, nl = g & 127;
    int t0 = nl * 64;
    size_t gidx = (size_t)(b * 24 + h) * 128 + nl;
    size_t hbase = (size_t)g * 4096;
    float alp = alpha[gidx];
    __shared__ short Cs[64 * 72];
    __shared__ short Bs[64 * 72];
    __shared__ short Ws[64 * 72];
    __shared__ short Xt[64 * 72];
    __shared__ float Acs[64];
    __shared__ float dte[64];
    int tid = threadIdx.x;
    if (tid < 64) {
        float a = Aarr[(size_t)(t0 + tid) * 24 + h] * (1.f - alp);
        for (int off = 1; off < 64; off <<= 1) {
            float u = __shfl_up(a, off, 64);
            if (tid >= off) a += u;
        }
        Acs[tid] = a;
        float total = __shfl(a, 63, 64);
        dte[tid] = expf(total - a);
        if (tid == 0) dchunk[gidx] = expf(total);
    }
    __syncthreads();
#pragma unroll
    for (int half = 0; half < 2; ++half) {
        int tau = tid + half * 256;
        int c = tau >> 3, s0 = (tau & 7) << 3;
        int t = t0 + c;
        const bf16* bp = xp + (size_t)t * XPS + h * 128;
        float ib = invB[t * 24 + h], ic2 = invC[t * 24 + h];
        float dc = dte[c];
        bf8v Bv = *(const bf8v*)(const void*)(bp + s0);
        bf8v Cv = *(const bf8v*)(const void*)(bp + 64 + s0);
        bf8v Xv = *(const bf8v*)(const void*)(xc + (size_t)t * DINNER + h * 64 + s0);
        bf8v Bsc, Csc;
#pragma unroll
        for (int u = 0; u < 8; ++u) {
            float bv = bs2f(Bv[u]) * ib;
            Bsc[u] = f2bs(bv);
            Csc[u] = f2bs(bs2f(Cv[u]) * ic2);
            Ws[(s0 + u) * 72 + c] = f2bs(bv * dc);
            Xt[(s0 + u) * 72 + c] = Xv[u];
        }
        *(bf8v*)&Bs[c * 72 + s0] = Bsc;
        *(bf8v*)&Cs[c * 72 + s0] = Csc;
    }
    __syncthreads();
    int w = tid >> 6, lane = tid & 63;
    int r16 = lane & 15, kq = (lane >> 4) << 3;
    int strip = w << 4;
    f4v acb[4], ach[4];
#pragma unroll
    for (int jt = 0; jt < 4; ++jt) {
        acb[jt] = (f4v){0.f, 0.f, 0.f, 0.f};
        ach[jt] = (f4v){0.f, 0.f, 0.f, 0.f};
    }
#pragma unroll
    for (int ks = 0; ks < 2; ++ks) {
        bf8v afc = *(const bf8v*)&Cs[(strip + r16) * 72 + ks * 32 + kq];
        bf8v afw = *(const bf8v*)&Ws[(strip + r16) * 72 + ks * 32 + kq];
#pragma unroll
        for (int jt = 0; jt < 4; ++jt) {
            bf8v bb = *(const bf8v*)&Bs[((jt << 4) + r16) * 72 + ks * 32 + kq];
            acb[jt] = __builtin_amdgcn_mfma_f32_16x16x32_bf16(afc, bb, acb[jt], 0, 0, 0);
            bf8v xx = *(const bf8v*)&Xt[((jt << 4) + r16) * 72 + ks * 32 + kq];
            ach[jt] = __builtin_amdgcn_mfma_f32_16x16x32_bf16(afw, xx, ach[jt], 0, 0, 0);
        }
    }
    int rbase = strip + ((lane >> 4) << 2);
#pragma unroll
    for (int dt = 0; dt < 4; ++dt) {
        int d = (dt << 4) + r16;
#pragma unroll
        for (int r = 0; r < 4; ++r)
            hf[hbase + (size_t)(rbase + r) * 64 + d] = f2bf(ach[dt][r]);
    }
    __syncthreads();
    short* Ms = Cs;
#pragma unroll
    for (int jt = 0; jt < 4; ++jt) {
        int j = (jt << 4) + r16;
        float aj = Acs[j];
#pragma unroll
        for (int r = 0; r < 4; ++r) {
            int i = rbase + r;
            float m = (j <= i) ? expf(Acs[i] - aj) * acb[jt][r] : 0.f;
            Ms[i * 72 + j] = f2bs(m);
        }
    }
    __syncthreads();
    f4v acy[4];
#pragma unroll
    for (int dt = 0; dt < 4; ++dt) acy[dt] = (f4v){0.f, 0.f, 0.f, 0.f};
#pragma unroll
    for (int ks = 0; ks < 2; ++ks) {
        bf8v afm = *(const bf8v*)&Ms[(strip + r16) * 72 + ks * 32 + kq];
#pragma unroll
        for (int dt = 0; dt < 4; ++dt) {
            bf8v xx = *(const bf8v*)&Xt[((dt << 4) + r16) * 72 + ks * 32 + kq];
            acy[dt] = __builtin_amdgcn_mfma_f32_16x16x32_bf16(afm, xx, acy[dt], 0, 0, 0);
        }
    }
#pragma unroll
    for (int dt = 0; dt < 4; ++dt) {
        int d = (dt << 4) + r16;
#pragma unroll
        for (int r = 0; r < 4; ++r) {
            int i = rbase + r;
            ybuf[(size_t)(t0 + i) * DINNER + h * 64 + d] = f2bf(acy[dt][r]);
        }
    }
}

// ---------------------------------------------------------------- chunk scan (batch-local, depth-4 pipeline)
__global__ __launch_bounds__(256) void k_scan(bf16* __restrict__ hf,
                                              const float* __restrict__ dchunk,
                                              int b) {
    int h = blockIdx.x >> 4;
    int e = ((blockIdx.x & 15) << 8) + threadIdx.x;
    size_t abase = (size_t)h * 128 * 4096 + e;
    const float* dcp = dchunk + (size_t)(b * 24 + h) * 128;
    float c = 0.f;
    float v0 = bf2f(hf[abase]);
    float v1 = bf2f(hf[abase + 1 * 4096]);
    float v2 = bf2f(hf[abase + 2 * 4096]);
    float v3 = bf2f(hf[abase + 3 * 4096]);
    for (int nl = 0; nl < 128; nl += 4) {
        float p0 = (nl + 4 < 128) ? bf2f(hf[abase + (size_t)(nl + 4) * 4096]) : 0.f;
        float p1 = (nl + 5 < 128) ? bf2f(hf[abase + (size_t)(nl + 5) * 4096]) : 0.f;
        float p2 = (nl + 6 < 128) ? bf2f(hf[abase + (size_t)(nl + 6) * 4096]) : 0.f;
        float p3 = (nl + 7 < 128) ? bf2f(hf[abase + (size_t)(nl + 7) * 4096]) : 0.f;
        hf[abase + (size_t)nl * 4096] = f2bf(c);
        c = dcp[nl] * c + v0;
        hf[abase + (size_t)(nl + 1) * 4096] = f2bf(c);
        c = dcp[nl + 1] * c + v1;
        hf[abase + (size_t)(nl + 2) * 4096] = f2bf(c);
        c = dcp[nl + 2] * c + v2;
        hf[abase + (size_t)(nl + 3) * 4096] = f2bf(c);
        c = dcp[nl + 3] * c + v3;
        v0 = p0; v1 = p1; v2 = p2; v3 = p3;
    }
}

// ---------------------------------------------------------------- Y_inter + gate (batch-local)
__global__ __launch_bounds__(256) void k_inter(const bf16* __restrict__ xp,
                                               const float* __restrict__ invC,
                                               const float* __restrict__ Aarr,
                                               const float* __restrict__ alpha,
                                               const bf16* __restrict__ hf,
                                               const bf16* __restrict__ zbuf,
                                               bf16* __restrict__ ybuf,
                                               int b) {
    int g = blockIdx.x;
    int h = g >> 7, nl = g & 127;
    int t0 = nl * 64;
    size_t gidx = (size_t)(b * 24 + h) * 128 + nl;
    size_t hbase = (size_t)g * 4096;
    float alp = alpha[gidx];
    __shared__ short Cs[64 * 72];
    __shared__ short Ht[64 * 72];
    __shared__ float dfs[64];
    int tid = threadIdx.x;
    if (tid < 64) {
        float a = Aarr[(size_t)(t0 + tid) * 24 + h] * (1.f - alp);
        for (int off = 1; off < 64; off <<= 1) {
            float u = __shfl_up(a, off, 64);
            if (tid >= off) a += u;
        }
        dfs[tid] = expf(a);
    }
#pragma unroll
    for (int half = 0; half < 2; ++half) {
        int tau = tid + half * 256;
        int c = tau >> 3, s0 = (tau & 7) << 3;
        int t = t0 + c;
        float ic2 = invC[t * 24 + h];
        bf8v Cv = *(const bf8v*)(const void*)(xp + (size_t)t * XPS + h * 128 + 64 + s0);
        bf8v Hv = *(const bf8v*)(const void*)(hf + hbase + (size_t)c * 64 + s0);
        bf8v Csc;
#pragma unroll
        for (int u = 0; u < 8; ++u) {
            Csc[u] = f2bs(bs2f(Cv[u]) * ic2);
            Ht[(s0 + u) * 72 + c] = Hv[u];
        }
        *(bf8v*)&Cs[c * 72 + s0] = Csc;
    }
    __syncthreads();
    int w = tid >> 6, lane = tid & 63;
    int r16 = lane & 15, kq = (lane >> 4) << 3;
    int strip = w << 4;
    f4v acc[4];
#pragma unroll
    for (int dt = 0; dt < 4; ++dt) acc[dt] = (f4v){0.f, 0.f, 0.f, 0.f};
#pragma unroll
    for (int ks = 0; ks < 2; ++ks) {
        bf8v af = *(const bf8v*)&Cs[(strip + r16) * 72 + ks * 32 + kq];
#pragma unroll
        for (int dt = 0; dt < 4; ++dt) {
            bf8v hfr = *(const bf8v*)&Ht[((dt << 4) + r16) * 72 + ks * 32 + kq];
            acc[dt] = __builtin_amdgcn_mfma_f32_16x16x32_bf16(af, hfr, acc[dt], 0, 0, 0);
        }
    }
    int ibase = strip + ((lane >> 4) << 2);
#pragma unroll
    for (int dt = 0; dt < 4; ++dt) {
        int d = (dt << 4) + r16;
#pragma unroll
        for (int r = 0; r < 4; ++r) {
            int i = ibase + r;
            float df = dfs[i];
            size_t yoff = (size_t)(t0 + i) * DINNER + h * 64 + d;
            float Y = clampf(bf2f(ybuf[yoff]) + df * acc[dt][r], -100.f, 100.f);
            float zz = bf2f(zbuf[yoff]);
            ybuf[yoff] = f2bf(Y / (1.f + expf(-zz)));
        }
    }
}

// ---------------------------------------------------------------- launch
extern "C" void kernel_launch(void* const* d_in, const int* in_sizes, int n_in,
                              void* d_out, int out_size, void* d_ws, size_t ws_size,
                              hipStream_t stream) {
    const float* hs     = (const float*)d_in[0];
    const float* norm_w = (const float*)d_in[1];
    const float* w1     = (const float*)d_in[2];
    const float* b1     = (const float*)d_in[3];
    const float* cw     = (const float*)d_in[4];
    const float* cbias  = (const float*)d_in[5];
    const float* w2     = (const float*)d_in[6];
    const float* b2     = (const float*)d_in[7];
    const float* A_log  = (const float*)d_in[8];
    const float* l2ab   = (const float*)d_in[9];
    const float* l2b    = (const float*)d_in[10];
    const float* ema0   = (const float*)d_in[11];
    const float* w3     = (const float*)d_in[12];
    const float* b3     = (const float*)d_in[13];
    const float* rg     = (const float*)d_in[14];
    float* out = (float*)d_out;

    char* base = (char*)d_ws;
    size_t off = 0;
    auto alloc = [&](size_t bytes) -> void* {
        void* p = base + off;
        off += (bytes + 255) & ~(size_t)255;
        return p;
    };
    bf16* w1bf  = (bf16*)alloc((size_t)2 * DINNER * DMODEL * 2);
    bf16* w2bf  = (bf16*)alloc((size_t)NPROJP * DINNER * 2);
    bf16* w3bf  = (bf16*)alloc((size_t)DMODEL * DINNER * 2);
    bf16* wdt   = (bf16*)alloc((size_t)128 * DINNER * 2);
    float* bdt  = (float*)alloc((size_t)128 * 4);
    bf16* xnb   = (bf16*)alloc((size_t)BT * DMODEL * 2);
    bf16* ybuf  = (bf16*)alloc((size_t)BT * DINNER * 2);
    bf16* hf    = (bf16*)alloc((size_t)NHEADS * 128 * 4096 * 2);
    bf16* dtb   = (bf16*)alloc((size_t)NTOK * 24 * 2);
    float* cs   = (float*)alloc((size_t)6144 * 4);
    float* alp  = (float*)alloc((size_t)6144 * 4);
    float* dch  = (float*)alloc((size_t)6144 * 4);
    bf16* xp    = (bf16*)alloc((size_t)NTOK * XPS * 2);
    float* Aarr = (float*)alloc((size_t)NTOK * 24 * 4);
    float* invB = (float*)alloc((size_t)NTOK * 24 * 4);
    float* invC = (float*)alloc((size_t)NTOK * 24 * 4);
    bf16* xbuf  = ybuf;
    bf16* xc_all = (bf16*)d_out;

    {
        int n1 = 2 * DINNER * DMODEL / 4, n2 = NPROJ * DINNER / 4, n3 = DMODEL * DINNER / 4;
        k_cvt<<<(n1 + 255) / 256, 256, 0, stream>>>(w1, w1bf, n1);
        k_cvt<<<(n2 + 255) / 256, 256, 0, stream>>>(w2, w2bf, n2);
        k_cvt<<<(n3 + 255) / 256, 256, 0, stream>>>(w3, w3bf, n3);
        int nz = (NPROJP - NPROJ) * DINNER;
        k_zero<<<(nz + 255) / 256, 256, 0, stream>>>(w2bf + (size_t)NPROJ * DINNER, nz);
        k_wdt<<<(128 * DINNER + 255) / 256, 256, 0, stream>>>(w2, b2, wdt, bdt);
    }

    const dim3 gXb(DINNER / 128, BT / 256);          // 12 x 32 (256-row tiles)
    const dim3 gOb(DMODEL / 128, BT / 128);          // 6 x 64  (128-row tiles)
    const dim3 gPall(NPROJP / 128, NTOK / 256);      // 25 x 64 (256-row tiles)
    const dim3 gDt(1, NTOK / 128);                   // 1 x 128 (dt GEMM, N=24)

    // ---------------- phase 1: front-end per batch; xc cached into d_out
    for (int bt = 0; bt < 2; ++bt) {
        size_t t0 = (size_t)bt * BT;
        k_rmsnorm<<<BT, 256, 0, stream>>>(hs + t0 * DMODEL, norm_w, xnb);
        k_mgemm2<bf16, 0><<<gXb, 512, 0, stream>>>(xnb, w1bf, b1, xbuf,
                                                   BT, DINNER, DMODEL);
        k_conv4<<<BT / 4, 192, 0, stream>>>(xbuf, cw, cbias, xc_all + t0 * DINNER);
    }
    // x_proj over all tokens (B/C to xp; dt via separate skinny GEMM)
    k_mgemm2<bf16, 2><<<gPall, 512, 0, stream>>>(xc_all, w2bf, b2, xp,
                                                 NTOK, NPROJ, DINNER);
    k_mgemm<bf16, 0><<<gDt, 256, 0, stream>>>(xc_all, wdt, bdt, dtb,
                                              NTOK, 24, DINNER, nullptr, nullptr);
    k_prep<<<NTOK * 24 / 4, 256, 0, stream>>>(xp, dtb, A_log, Aarr, invB, invC);
    k_surprise_all<<<6144, 256, 0, stream>>>(xp, xc_all, invB, cs);
    k_alpha<<<24, 256, 0, stream>>>(cs, ema0, l2ab, l2b, alp);

    // ---------------- phase 2: batch 1 first (xnb still holds batch-1 xn), then batch 0
    for (int pass = 0; pass < 2; ++pass) {
        int bt = 1 - pass;
        size_t t0 = (size_t)bt * BT;
        bf16* xc = xc_all + t0 * DINNER;
        bf16* zseg = xc;
        const bf16* xpS = xp + t0 * XPS;
        const float* AarrS = Aarr + t0 * 24;
        const float* invBS = invB + t0 * 24;
        const float* invCS = invC + t0 * 24;
        k_chunk<<<NHEADS * 128, 256, 0, stream>>>(xpS, xc, invBS, invCS, AarrS, alp,
                                                  ybuf, hf, dch, bt);
        if (bt == 0)
            k_rmsnorm<<<BT, 256, 0, stream>>>(hs + t0 * DMODEL, norm_w, xnb);
        k_mgemm2<bf16, 0><<<gXb, 512, 0, stream>>>(xnb, w1bf + (size_t)DINNER * DMODEL,
                                                   b1 + DINNER, zseg,
                                                   BT, DINNER, DMODEL);
        k_scan<<<384, 256, 0, stream>>>(hf, dch, bt);
        k_inter<<<NHEADS * 128, 256, 0, stream>>>(xpS, invCS, AarrS, alp, hf, zseg, ybuf, bt);
        k_mgemm<float, 1><<<gOb, 256, 0, stream>>>(ybuf, w3bf, b3, out + t0 * DMODEL,
                                                   BT, DMODEL, DINNER,
                                                   hs + t0 * DMODEL, rg);
    }
}